// Round 1
// baseline (4605.639 us; speedup 1.0000x reference)
//
#include <hip/hip_runtime.h>
#include <hip/hip_bf16.h>
#include <cstdint>
#include <math.h>

#define BB 2
#define TT 1024
#define DIMM 768
#define NHEADS 8
#define DHH 96
#define MLPD 3072
#define NN 2048   // 2*T

static constexpr float kEps = 1e-6f;

__device__ __forceinline__ float siluf(float x){ return x / (1.f + expf(-x)); }
__device__ __forceinline__ float geluf(float x){ return 0.5f*x*(1.f + erff(x*0.7071067811865475f)); }
__device__ __forceinline__ float bf16_rne(float x){
  uint32_t u = __float_as_uint(x);
  u = (u + 0x7fffu + ((u >> 16) & 1u)) & 0xffff0000u;
  return __uint_as_float(u);
}

// ---------------- modulation MLP ----------------
// h2[b][o] = silu( sum_j silu(p_emb[b][j]) * w1[j][o] + b1[o] ),  o in [0,512)
__global__ __launch_bounds__(256) void mod_stage1_k(
    const float* __restrict__ p_emb, const float* __restrict__ w1,
    const float* __restrict__ b1, float* __restrict__ h2){
  __shared__ float sp[1024];
  const int b = blockIdx.x >> 1;
  const int obase = (blockIdx.x & 1) * 256;
  for (int i = threadIdx.x; i < 1024; i += 256)
    sp[i] = siluf(p_emb[b*1024 + i]);
  __syncthreads();
  const int o = obase + threadIdx.x;
  float acc = 0.f;
  for (int j = 0; j < 1024; ++j) acc += sp[j] * w1[j*512 + o];
  h2[b*512 + o] = siluf(acc + b1[o]);
}

// mod[b][o] = sum_j h2[b][j]*w2[j][o] + b2[o],  o in [0,9216)
__global__ __launch_bounds__(256) void mod_stage2_k(
    const float* __restrict__ h2, const float* __restrict__ w2,
    const float* __restrict__ b2, float* __restrict__ mod){
  __shared__ float sh[512];
  const int b = blockIdx.x / 36;
  const int obase = (blockIdx.x % 36) * 256;
  for (int i = threadIdx.x; i < 512; i += 256)
    sh[i] = h2[b*512 + i];
  __syncthreads();
  const int o = obase + threadIdx.x;
  float acc = 0.f;
  for (int j = 0; j < 512; ++j) acc += sh[j] * w2[j*9216 + o];
  mod[b*9216 + o] = acc + b2[o];
}

// ---------------- RMSNorm + modulation ----------------
// out = rms(x)*w*(1+mod[cs]) + mod[ch]; row = b*T+t, 768 wide, 256 threads
__global__ __launch_bounds__(256) void rmsnorm_mod_k(
    const float* __restrict__ x, const float* __restrict__ w,
    const float* __restrict__ mod, int cs, int ch, float* __restrict__ out){
  const int row = blockIdx.x;
  const int b = row >> 10;
  const int tid = threadIdx.x;
  const float* xr = x + (size_t)row * DIMM;
  float v0 = xr[tid], v1 = xr[tid + 256], v2 = xr[tid + 512];
  float ss = v0*v0 + v1*v1 + v2*v2;
  __shared__ float red[4];
  for (int m = 1; m < 64; m <<= 1) ss += __shfl_xor(ss, m, 64);
  if ((tid & 63) == 0) red[tid >> 6] = ss;
  __syncthreads();
  float tot = red[0] + red[1] + red[2] + red[3];
  float rms = rsqrtf(tot * (1.f/768.f) + kEps);
  const float* ms = mod + (size_t)b*9216 + (size_t)cs*768;
  const float* mh = mod + (size_t)b*9216 + (size_t)ch*768;
  float* orow = out + (size_t)row * DIMM;
  orow[tid]       = v0*rms*w[tid]      *(1.f+ms[tid])       + mh[tid];
  orow[tid + 256] = v1*rms*w[tid+256]  *(1.f+ms[tid+256])   + mh[tid+256];
  orow[tid + 512] = v2*rms*w[tid+512]  *(1.f+ms[tid+512])   + mh[tid+512];
}

// ---------------- generic fp32 GEMM: C = A@W + bias (optional GELU) --------
// A[M,K] row-major, W[K,N] row-major. 64x64 tile, BK=16, 4x4 per thread.
template<int ACT>
__global__ __launch_bounds__(256) void gemm_k(
    const float* __restrict__ A, const float* __restrict__ W,
    const float* __restrict__ bias, float* __restrict__ C,
    int M, int N, int K){
  __shared__ float As[64][17];
  __shared__ float Ws[16][65];
  const int tid = threadIdx.x;
  const int bx = blockIdx.x, by = blockIdx.y;
  const int tx = tid & 15, ty = tid >> 4;
  const int arow = tid >> 2, acol = (tid & 3) * 4;
  const int wrow = tid >> 4, wcol = (tid & 15) * 4;
  float acc[4][4] = {};
  const float* Ap = A + (size_t)(by*64 + arow)*K + acol;
  const float* Wp = W + (size_t)wrow*N + bx*64 + wcol;
  for (int k0 = 0; k0 < K; k0 += 16){
    float4 av = *(const float4*)(Ap + k0);
    float4 wv = *(const float4*)(Wp + (size_t)k0*N);
    As[arow][acol+0]=av.x; As[arow][acol+1]=av.y; As[arow][acol+2]=av.z; As[arow][acol+3]=av.w;
    Ws[wrow][wcol+0]=wv.x; Ws[wrow][wcol+1]=wv.y; Ws[wrow][wcol+2]=wv.z; Ws[wrow][wcol+3]=wv.w;
    __syncthreads();
    #pragma unroll
    for (int kk = 0; kk < 16; ++kk){
      float a0 = As[ty*4+0][kk], a1 = As[ty*4+1][kk], a2 = As[ty*4+2][kk], a3 = As[ty*4+3][kk];
      float w0 = Ws[kk][tx*4+0], w1 = Ws[kk][tx*4+1], w2 = Ws[kk][tx*4+2], w3 = Ws[kk][tx*4+3];
      acc[0][0] += a0*w0; acc[0][1] += a0*w1; acc[0][2] += a0*w2; acc[0][3] += a0*w3;
      acc[1][0] += a1*w0; acc[1][1] += a1*w1; acc[1][2] += a1*w2; acc[1][3] += a1*w3;
      acc[2][0] += a2*w0; acc[2][1] += a2*w1; acc[2][2] += a2*w2; acc[2][3] += a2*w3;
      acc[3][0] += a3*w0; acc[3][1] += a3*w1; acc[3][2] += a3*w2; acc[3][3] += a3*w3;
    }
    __syncthreads();
  }
  #pragma unroll
  for (int i = 0; i < 4; ++i){
    #pragma unroll
    for (int j = 0; j < 4; ++j){
      float v = acc[i][j] + bias[bx*64 + tx*4 + j];
      if (ACT == 1) v = geluf(v);
      C[(size_t)(by*64 + ty*4 + i)*N + bx*64 + tx*4 + j] = v;
    }
  }
}

// ---------------- head split + RoPE + L2norm*scale ----------------
// qkv1/qkv2: [B*T, 2304]. Out Q,K,V: [B,H,N,dh] flat, N = 2048.
__global__ __launch_bounds__(256) void build_qkv_k(
    const float* __restrict__ qkv1, const float* __restrict__ qkv2,
    const float* __restrict__ qk_scale,
    float* __restrict__ Q, float* __restrict__ K, float* __restrict__ V){
  const int wid = threadIdx.x >> 6;
  const int lane = threadIdx.x & 63;
  const int row = blockIdx.x * 4 + wid;         // (b*8+h)*2048 + n
  const int n = row & 2047;
  const int h = (row >> 11) & 7;
  const int b = row >> 14;
  const float* src = (n < TT) ? (qkv1 + ((size_t)b*TT + n) * 2304)
                              : (qkv2 + ((size_t)b*TT + (n - TT)) * 2304);
  const int col = h * DHH;
  const bool act = lane < 48;
  float q0=0,q1=0,k0=0,k1=0,v0=0,v1=0,c=1.f,s=0.f,sc0=0,sc1=0;
  if (act){
    q0 = src[col + lane];        q1 = src[col + lane + 48];
    k0 = src[768 + col + lane];  k1 = src[768 + col + lane + 48];
    v0 = src[1536 + col + lane]; v1 = src[1536 + col + lane + 48];
    float inv = bf16_rne((float)(1.0 / pow(10000.0, (2.0 * lane) / 96.0)));
    float ang = (float)n * inv;
    c = cosf(ang); s = sinf(ang);
    sc0 = qk_scale[lane]; sc1 = qk_scale[lane + 48];
  }
  float qr0 = q0*c - q1*s, qr1 = q1*c + q0*s;
  float kr0 = k0*c - k1*s, kr1 = k1*c + k0*s;
  float ssq = qr0*qr0 + qr1*qr1;
  float ssk = kr0*kr0 + kr1*kr1;
  for (int m = 1; m < 64; m <<= 1){ ssq += __shfl_xor(ssq, m, 64); ssk += __shfl_xor(ssk, m, 64); }
  float rq = 1.f / fmaxf(sqrtf(ssq), 1e-12f);
  float rk = 1.f / fmaxf(sqrtf(ssk), 1e-12f);
  if (act){
    size_t base = (size_t)row * DHH;
    Q[base + lane]      = qr0*rq*sc0;  Q[base + lane + 48] = qr1*rq*sc1;
    K[base + lane]      = kr0*rk*sc0;  K[base + lane + 48] = kr1*rk*sc1;
    V[base + lane]      = v0;          V[base + lane + 48] = v1;
  }
}

// ---------------- flash-style attention (fp32) ----------------
// block: one (b,h) x 16 query rows; key tiles of 64. Output AO[B, N, DIM] (head-merged).
#define QR 16
#define KT 64
__global__ __launch_bounds__(256) void attn_k(
    const float* __restrict__ Q, const float* __restrict__ K,
    const float* __restrict__ V, float* __restrict__ AO){
  const int blk = blockIdx.x;
  const int qb = blk & 127;          // N/QR = 128
  const int bh = blk >> 7;           // b*8+h
  const int h = bh & 7, b = bh >> 3;
  const float* Qb = Q + (size_t)bh * NN * DHH;
  const float* Kb = K + (size_t)bh * NN * DHH;
  const float* Vb = V + (size_t)bh * NN * DHH;
  __shared__ float Qs[QR][DHH + 1];
  __shared__ float Ks[KT][DHH + 1];
  __shared__ float Vs[KT][DHH + 1];
  __shared__ float Ss[QR][KT + 1];
  __shared__ float mrow[QR], lrow[QR], crow[QR];
  const int tid = threadIdx.x;
  const float* Qt = Qb + (size_t)qb * QR * DHH;
  for (int i = tid; i < QR * DHH; i += 256) Qs[i / DHH][i % DHH] = Qt[i];
  if (tid < QR){ mrow[tid] = -1e30f; lrow[tid] = 0.f; }
  const int r = tid >> 4, g = tid & 15;
  float oacc[6] = {0.f,0.f,0.f,0.f,0.f,0.f};
  const float sscale = 0.1020620726159658f;  // 96^-0.5
  __syncthreads();
  for (int kb = 0; kb < NN; kb += KT){
    for (int i = tid; i < KT * DHH; i += 256){
      int rr = i / DHH, dd = i % DHH;
      Ks[rr][dd] = Kb[(size_t)(kb + rr)*DHH + dd];
      Vs[rr][dd] = Vb[(size_t)(kb + rr)*DHH + dd];
    }
    __syncthreads();
    #pragma unroll
    for (int jj = 0; jj < 4; ++jj){
      int j = g*4 + jj;
      float sacc = 0.f;
      #pragma unroll
      for (int d = 0; d < DHH; ++d) sacc += Qs[r][d] * Ks[j][d];
      Ss[r][j] = sacc * sscale;
    }
    __syncthreads();
    if (g == 0){
      float m = mrow[r], mx = m;
      for (int j = 0; j < KT; ++j) mx = fmaxf(mx, Ss[r][j]);
      float c = expf(m - mx);
      float l = lrow[r] * c, psum = 0.f;
      for (int j = 0; j < KT; ++j){ float p = expf(Ss[r][j] - mx); Ss[r][j] = p; psum += p; }
      lrow[r] = l + psum; mrow[r] = mx; crow[r] = c;
    }
    __syncthreads();
    float c = crow[r];
    #pragma unroll
    for (int d6 = 0; d6 < 6; ++d6) oacc[d6] *= c;
    for (int j = 0; j < KT; ++j){
      float p = Ss[r][j];
      #pragma unroll
      for (int d6 = 0; d6 < 6; ++d6) oacc[d6] += p * Vs[j][g*6 + d6];
    }
    __syncthreads();
  }
  float linv = 1.f / lrow[r];
  const int n = qb * QR + r;
  float* dst = AO + ((size_t)b*NN + n)*DIMM + h*DHH + g*6;
  #pragma unroll
  for (int d6 = 0; d6 < 6; ++d6) dst[d6] = oacc[d6] * linv;
}

// ---------------- gated residual: out = x + P[stream rows]*m_g ----------------
__global__ __launch_bounds__(256) void residual_k(
    const float* __restrict__ x, const float* __restrict__ P,
    const float* __restrict__ mod, int cg, int stream, float* __restrict__ out){
  const int idx = blockIdx.x * 256 + threadIdx.x;   // B*T*DIM
  const int d = idx % DIMM;
  const int bt = idx / DIMM;
  const int b = bt >> 10, t = bt & 1023;
  const int prow = b*NN + stream*TT + t;
  float gv = mod[(size_t)b*9216 + (size_t)cg*768 + d];
  out[idx] = x[idx] + P[(size_t)prow*DIMM + d] * gv;
}

// ---------------- final: out += Mx * m_g ----------------
__global__ __launch_bounds__(256) void final_add_k(
    const float* __restrict__ Mx, const float* __restrict__ mod, int cg,
    float* __restrict__ out){
  const int idx = blockIdx.x * 256 + threadIdx.x;
  const int d = idx % DIMM;
  const int b = (idx / DIMM) >> 10;
  float gv = mod[(size_t)b*9216 + (size_t)cg*768 + d];
  out[idx] += Mx[idx] * gv;
}

// ---------------- workspace layout (floats) ----------------
static constexpr size_t OFF_H2   = 0;          // 1024
static constexpr size_t OFF_MOD  = 1024;       // 18432
static constexpr size_t OFF_XM1  = 32768;      // 1,572,864 (reused as xn1)
static constexpr size_t OFF_XM2  = OFF_XM1 + 1572864;
static constexpr size_t OFF_QKV1 = OFF_XM2 + 1572864;   // 4,718,592
static constexpr size_t OFF_QKV2 = OFF_QKV1 + 4718592;
static constexpr size_t OFF_Q    = OFF_QKV2 + 4718592;  // 3,145,728
static constexpr size_t OFF_K    = OFF_Q + 3145728;
static constexpr size_t OFF_V    = OFF_K + 3145728;
static constexpr size_t OFF_AO   = OFF_V + 3145728;     // 3,145,728 (reused as M1)
static constexpr size_t OFF_P    = OFF_AO + 3145728;    // 3,145,728 (reused as M2)
static constexpr size_t OFF_HID1 = OFF_QKV1;            // 6,291,456 <= 9,437,184
static constexpr size_t OFF_HID2 = OFF_Q;               // 6,291,456 <= Q+K

extern "C" void kernel_launch(void* const* d_in, const int* in_sizes, int n_in,
                              void* d_out, int out_size, void* d_ws, size_t ws_size,
                              hipStream_t stream){
  const float* x_s1    = (const float*)d_in[0];
  const float* x_s2    = (const float*)d_in[1];
  const float* p_emb   = (const float*)d_in[2];
  const float* mod_w1  = (const float*)d_in[3];
  const float* mod_b1  = (const float*)d_in[4];
  const float* mod_w2  = (const float*)d_in[5];
  const float* mod_b2  = (const float*)d_in[6];
  const float* n11_w   = (const float*)d_in[7];
  const float* n12_w   = (const float*)d_in[8];
  const float* qkv_w   = (const float*)d_in[9];
  const float* qkv_b   = (const float*)d_in[10];
  const float* qkv2_w  = (const float*)d_in[11];
  const float* qkv2_b  = (const float*)d_in[12];
  const float* qk_sc   = (const float*)d_in[13];
  const float* out_w   = (const float*)d_in[14];
  const float* out_b   = (const float*)d_in[15];
  const float* n21_w   = (const float*)d_in[16];
  const float* n22_w   = (const float*)d_in[17];
  const float* m1w1    = (const float*)d_in[18];
  const float* m1b1    = (const float*)d_in[19];
  const float* m1w2    = (const float*)d_in[20];
  const float* m1b2    = (const float*)d_in[21];
  const float* m2w1    = (const float*)d_in[22];
  const float* m2b1    = (const float*)d_in[23];
  const float* m2w2    = (const float*)d_in[24];
  const float* m2b2    = (const float*)d_in[25];

  float* ws   = (float*)d_ws;
  float* h2b  = ws + OFF_H2;
  float* modb = ws + OFF_MOD;
  float* xm1  = ws + OFF_XM1;
  float* xm2  = ws + OFF_XM2;
  float* qkv1 = ws + OFF_QKV1;
  float* qkv2 = ws + OFF_QKV2;
  float* Qb   = ws + OFF_Q;
  float* Kb   = ws + OFF_K;
  float* Vb   = ws + OFF_V;
  float* AO   = ws + OFF_AO;
  float* Pb   = ws + OFF_P;
  float* H1   = ws + OFF_HID1;
  float* H2   = ws + OFF_HID2;
  float* M1   = ws + OFF_AO;   // reuse
  float* M2   = ws + OFF_P;    // reuse

  float* out0 = (float*)d_out;             // x1 + mlp1*m3g, B*T*DIM
  float* out1 = out0 + (size_t)BB*TT*DIMM; // x2 + mlp2*m4g

  // modulation MLP
  mod_stage1_k<<<4, 256, 0, stream>>>(p_emb, mod_w1, mod_b1, h2b);
  mod_stage2_k<<<72, 256, 0, stream>>>(h2b, mod_w2, mod_b2, modb);

  // pre-attention norms (chunks: m1s=0,m1h=1 / m2s=3,m2h=4)
  rmsnorm_mod_k<<<BB*TT, 256, 0, stream>>>(x_s1, n11_w, modb, 0, 1, xm1);
  rmsnorm_mod_k<<<BB*TT, 256, 0, stream>>>(x_s2, n12_w, modb, 3, 4, xm2);

  // QKV GEMMs: [2048,768]@[768,2304]
  gemm_k<0><<<dim3(36, 32), 256, 0, stream>>>(xm1, qkv_w,  qkv_b,  qkv1, 2048, 2304, 768);
  gemm_k<0><<<dim3(36, 32), 256, 0, stream>>>(xm2, qkv2_w, qkv2_b, qkv2, 2048, 2304, 768);

  // heads + RoPE + l2norm*scale
  build_qkv_k<<<(BB*NHEADS*NN)/4, 256, 0, stream>>>(qkv1, qkv2, qk_sc, Qb, Kb, Vb);

  // attention -> AO [B, N, DIM]
  attn_k<<<BB*NHEADS*(NN/QR), 256, 0, stream>>>(Qb, Kb, Vb, AO);

  // out projection: [4096,768]@[768,768]
  gemm_k<0><<<dim3(12, 64), 256, 0, stream>>>(AO, out_w, out_b, Pb, 4096, 768, 768);

  // gated residual -> d_out holds x1, x2 (chunks m1g=2, m2g=5)
  residual_k<<<6144, 256, 0, stream>>>(x_s1, Pb, modb, 2, 0, out0);
  residual_k<<<6144, 256, 0, stream>>>(x_s2, Pb, modb, 5, 1, out1);

  // post-attention norms (m3s=6,m3h=7 / m4s=9,m4h=10)
  rmsnorm_mod_k<<<BB*TT, 256, 0, stream>>>(out0, n21_w, modb, 6, 7, xm1);
  rmsnorm_mod_k<<<BB*TT, 256, 0, stream>>>(out1, n22_w, modb, 9, 10, xm2);

  // MLPs: GELU GEMM then down-proj
  gemm_k<1><<<dim3(48, 32), 256, 0, stream>>>(xm1, m1w1, m1b1, H1, 2048, 3072, 768);
  gemm_k<0><<<dim3(12, 32), 256, 0, stream>>>(H1, m1w2, m1b2, M1, 2048, 768, 3072);
  gemm_k<1><<<dim3(48, 32), 256, 0, stream>>>(xm2, m2w1, m2b1, H2, 2048, 3072, 768);
  gemm_k<0><<<dim3(12, 32), 256, 0, stream>>>(H2, m2w2, m2b2, M2, 2048, 768, 3072);

  // final gated adds (m3g=8, m4g=11)
  final_add_k<<<6144, 256, 0, stream>>>(M1, modb, 8, out0);
  final_add_k<<<6144, 256, 0, stream>>>(M2, modb, 11, out1);
}

// Round 2
// 410.475 us; speedup vs baseline: 11.2203x; 11.2203x over previous
//
#include <hip/hip_runtime.h>
#include <hip/hip_bf16.h>
#include <cstdint>
#include <math.h>

#define BB 2
#define TT 1024
#define DIMM 768
#define NHEADS 8
#define DHH 96
#define MLPD 3072
#define NN 2048   // 2*T

typedef unsigned short u16;
using short8 = __attribute__((ext_vector_type(8))) short;
using f32x4  = __attribute__((ext_vector_type(4))) float;
using f32x16 = __attribute__((ext_vector_type(16))) float;
using int4v  = __attribute__((ext_vector_type(4))) int;
union S8I4 { int4v i; short8 s; };

static constexpr float kEps = 1e-6f;

__device__ __forceinline__ float siluf(float x){ return x / (1.f + expf(-x)); }
__device__ __forceinline__ float geluf(float x){ return 0.5f*x*(1.f + erff(x*0.7071067811865475f)); }
__device__ __forceinline__ float bf16_rne(float x){
  uint32_t u = __float_as_uint(x);
  u = (u + 0x7fffu + ((u >> 16) & 1u)) & 0xffff0000u;
  return __uint_as_float(u);
}
__device__ __forceinline__ u16 f2b(float x){
  uint32_t u = __float_as_uint(x);
  return (u16)((u + 0x7fffu + ((u >> 16) & 1u)) >> 16);
}
__device__ __forceinline__ float b2f(u16 b){
  return __uint_as_float(((uint32_t)b) << 16);
}
__device__ __forceinline__ int cvtpk(float lo, float hi){
  int d; asm("v_cvt_pk_bf16_f32 %0, %1, %2" : "=v"(d) : "v"(lo), "v"(hi)); return d;
}
__device__ __forceinline__ void gload16(const void* g, void* l){
  __builtin_amdgcn_global_load_lds((const __attribute__((address_space(1))) unsigned int*)g,
                                   (__attribute__((address_space(3))) unsigned int*)l, 16, 0, 0);
}

// ---------------- modulation MLP (fp32, tiny) ----------------
__global__ __launch_bounds__(256) void mod_stage1_k(
    const float* __restrict__ p_emb, const float* __restrict__ w1,
    const float* __restrict__ b1, float* __restrict__ h2){
  __shared__ float sp[1024];
  const int b = blockIdx.x >> 1;
  const int obase = (blockIdx.x & 1) * 256;
  for (int i = threadIdx.x; i < 1024; i += 256)
    sp[i] = siluf(p_emb[b*1024 + i]);
  __syncthreads();
  const int o = obase + threadIdx.x;
  float acc = 0.f;
  for (int j = 0; j < 1024; ++j) acc += sp[j] * w1[j*512 + o];
  h2[b*512 + o] = siluf(acc + b1[o]);
}

__global__ __launch_bounds__(256) void mod_stage2_k(
    const float* __restrict__ h2, const float* __restrict__ w2,
    const float* __restrict__ b2, float* __restrict__ mod){
  __shared__ float sh[512];
  const int b = blockIdx.x / 36;
  const int obase = (blockIdx.x % 36) * 256;
  for (int i = threadIdx.x; i < 512; i += 256)
    sh[i] = h2[b*512 + i];
  __syncthreads();
  const int o = obase + threadIdx.x;
  float acc = 0.f;
  for (int j = 0; j < 512; ++j) acc += sh[j] * w2[j*9216 + o];
  mod[b*9216 + o] = acc + b2[o];
}

// ---------------- weight convert+transpose: W[K][N] f32 -> Wt[N][K] bf16 ----
__global__ __launch_bounds__(256) void wt_k(
    const float* __restrict__ W, u16* __restrict__ Wt, int K, int N){
  __shared__ float t[32][33];
  const int k0 = blockIdx.y*32, n0 = blockIdx.x*32;
  const int tx = threadIdx.x & 31, ty = threadIdx.x >> 5;
  for (int i = ty; i < 32; i += 8)
    t[i][tx] = W[(size_t)(k0+i)*N + n0 + tx];
  __syncthreads();
  for (int i = ty; i < 32; i += 8)
    Wt[(size_t)(n0+i)*K + k0 + tx] = f2b(t[tx][i]);
}

// ---------------- RMSNorm + modulation -> bf16 ----------------
__global__ __launch_bounds__(256) void rmsnorm_mod_k(
    const float* __restrict__ x, const float* __restrict__ w,
    const float* __restrict__ mod, int cs, int ch, u16* __restrict__ out){
  const int row = blockIdx.x;
  const int b = row >> 10;
  const int tid = threadIdx.x;
  const float* xr = x + (size_t)row * DIMM;
  float v0 = xr[tid], v1 = xr[tid + 256], v2 = xr[tid + 512];
  float ss = v0*v0 + v1*v1 + v2*v2;
  __shared__ float red[4];
  for (int m = 1; m < 64; m <<= 1) ss += __shfl_xor(ss, m, 64);
  if ((tid & 63) == 0) red[tid >> 6] = ss;
  __syncthreads();
  float tot = red[0] + red[1] + red[2] + red[3];
  float rms = rsqrtf(tot * (1.f/768.f) + kEps);
  const float* ms = mod + (size_t)b*9216 + (size_t)cs*768;
  const float* mh = mod + (size_t)b*9216 + (size_t)ch*768;
  u16* orow = out + (size_t)row * DIMM;
  orow[tid]       = f2b(v0*rms*w[tid]      *(1.f+ms[tid])       + mh[tid]);
  orow[tid + 256] = f2b(v1*rms*w[tid+256]  *(1.f+ms[tid+256])   + mh[tid+256]);
  orow[tid + 512] = f2b(v2*rms*w[tid+512]  *(1.f+ms[tid+512])   + mh[tid+512]);
}

// ---------------- bf16 MFMA GEMM: C = A@Wt^T + bias (opt GELU) -------------
// A[M,K] bf16 row-major, Wt[N,K] bf16 row-major (pre-transposed weights).
// 128x128 tile, BK=32, 4 waves (2x2), each wave 64x64 via 4x4 of 16x16x32.
template<int ACT, int OUTBF, int DUAL>
__global__ __launch_bounds__(256) void gemm_bf16_k(
    const u16* __restrict__ A0, const u16* __restrict__ Bt0,
    const float* __restrict__ bias0, void* __restrict__ C0,
    const u16* __restrict__ A1, const u16* __restrict__ Bt1,
    const float* __restrict__ bias1, void* __restrict__ C1,
    int M, int N, int K){
  __shared__ u16 As[2][128*32];
  __shared__ u16 Bs[2][128*32];
  const u16* A    = (DUAL && blockIdx.z) ? A1 : A0;
  const u16* Bt   = (DUAL && blockIdx.z) ? Bt1 : Bt0;
  const float* bias = (DUAL && blockIdx.z) ? bias1 : bias0;
  void* C         = (DUAL && blockIdx.z) ? C1 : C0;
  const int tid = threadIdx.x;
  const int w = tid >> 6, l = tid & 63;
  const int m0 = blockIdx.y*128, n0 = blockIdx.x*128;
  const int wr = w >> 1, wc = w & 1;
  const int la = l & 15, hi4 = l >> 4;
  f32x4 acc[4][4] = {};
  const int nk = K >> 5;
  // prologue: stage tile 0
  #pragma unroll
  for (int it = 0; it < 2; ++it){
    const int sb = w*128 + it*64;
    const int s = sb + l;
    const int row = s >> 2, sl = s & 3;
    gload16(A  + (size_t)(m0+row)*K + sl*8, &As[0][sb*8]);
    gload16(Bt + (size_t)(n0+row)*K + sl*8, &Bs[0][sb*8]);
  }
  __syncthreads();
  for (int kt = 0; kt < nk; ++kt){
    const int cur = kt & 1;
    if (kt + 1 < nk){
      const int k0n = (kt+1) << 5;
      #pragma unroll
      for (int it = 0; it < 2; ++it){
        const int sb = w*128 + it*64;
        const int s = sb + l;
        const int row = s >> 2, sl = s & 3;
        gload16(A  + (size_t)(m0+row)*K + k0n + sl*8, &As[cur^1][sb*8]);
        gload16(Bt + (size_t)(n0+row)*K + k0n + sl*8, &Bs[cur^1][sb*8]);
      }
    }
    short8 af[4], bf[4];
    #pragma unroll
    for (int mi = 0; mi < 4; ++mi)
      af[mi] = *(const short8*)((const char*)&As[cur][0] + (wr*64 + mi*16 + la)*64 + hi4*16);
    #pragma unroll
    for (int ni = 0; ni < 4; ++ni)
      bf[ni] = *(const short8*)((const char*)&Bs[cur][0] + (wc*64 + ni*16 + la)*64 + hi4*16);
    #pragma unroll
    for (int mi = 0; mi < 4; ++mi)
      #pragma unroll
      for (int ni = 0; ni < 4; ++ni)
        acc[mi][ni] = __builtin_amdgcn_mfma_f32_16x16x32_bf16(af[mi], bf[ni], acc[mi][ni], 0, 0, 0);
    __syncthreads();
  }
  // epilogue
  #pragma unroll
  for (int mi = 0; mi < 4; ++mi){
    #pragma unroll
    for (int ni = 0; ni < 4; ++ni){
      const int n = n0 + wc*64 + ni*16 + la;
      const float bv = bias[n];
      #pragma unroll
      for (int rr = 0; rr < 4; ++rr){
        const int m = m0 + wr*64 + mi*16 + hi4*4 + rr;
        float v = acc[mi][ni][rr] + bv;
        if (ACT == 1) v = geluf(v);
        if (OUTBF) ((u16*)C)[(size_t)m*N + n] = f2b(v);
        else       ((float*)C)[(size_t)m*N + n] = v;
      }
    }
  }
}

// ---------------- head split + RoPE + L2norm*scale (bf16 io) ---------------
// qkv bf16 [B*T, 2304] -> Q,K (bf16, Q has 96^-0.5 folded), Vtmp bf16 [bh][n][96]
__global__ __launch_bounds__(256) void build_qkv_k(
    const u16* __restrict__ qkv1, const u16* __restrict__ qkv2,
    const float* __restrict__ qk_scale,
    u16* __restrict__ Q, u16* __restrict__ K, u16* __restrict__ V){
  const int wid = threadIdx.x >> 6;
  const int lane = threadIdx.x & 63;
  const int row = blockIdx.x * 4 + wid;         // (b*8+h)*2048 + n
  const int n = row & 2047;
  const int h = (row >> 11) & 7;
  const int b = row >> 14;
  const u16* src = (n < TT) ? (qkv1 + ((size_t)b*TT + n) * 2304)
                            : (qkv2 + ((size_t)b*TT + (n - TT)) * 2304);
  const int col = h * DHH;
  const bool act = lane < 48;
  float q0=0,q1=0,k0=0,k1=0,v0=0,v1=0,c=1.f,s=0.f,sc0=0,sc1=0;
  if (act){
    q0 = b2f(src[col + lane]);        q1 = b2f(src[col + lane + 48]);
    k0 = b2f(src[768 + col + lane]);  k1 = b2f(src[768 + col + lane + 48]);
    v0 = b2f(src[1536 + col + lane]); v1 = b2f(src[1536 + col + lane + 48]);
    float inv = bf16_rne((float)(1.0 / pow(10000.0, (2.0 * lane) / 96.0)));
    float ang = (float)n * inv;
    c = cosf(ang); s = sinf(ang);
    sc0 = qk_scale[lane]; sc1 = qk_scale[lane + 48];
  }
  float qr0 = q0*c - q1*s, qr1 = q1*c + q0*s;
  float kr0 = k0*c - k1*s, kr1 = k1*c + k0*s;
  float ssq = qr0*qr0 + qr1*qr1;
  float ssk = kr0*kr0 + kr1*kr1;
  for (int m = 1; m < 64; m <<= 1){ ssq += __shfl_xor(ssq, m, 64); ssk += __shfl_xor(ssk, m, 64); }
  float rq = 1.f / fmaxf(sqrtf(ssq), 1e-12f);
  float rk = 1.f / fmaxf(sqrtf(ssk), 1e-12f);
  const float sscale = 0.1020620726159658f;  // 96^-0.5 folded into Q
  if (act){
    size_t base = (size_t)row * DHH;
    Q[base + lane]      = f2b(qr0*rq*sc0*sscale);  Q[base + lane + 48] = f2b(qr1*rq*sc1*sscale);
    K[base + lane]      = f2b(kr0*rk*sc0);         K[base + lane + 48] = f2b(kr1*rk*sc1);
    V[base + lane]      = f2b(v0);                 V[base + lane + 48] = f2b(v1);
  }
}

// ---------------- V transpose: Vtmp[bh][n][96] -> Vt[bh][96][2048] ----------
__global__ __launch_bounds__(256) void vtrans_k(
    const u16* __restrict__ Vtmp, u16* __restrict__ Vt){
  __shared__ u16 t[32][33];
  const int bh = blockIdx.z;
  const int n0 = blockIdx.x*32, d0 = blockIdx.y*32;
  const int tx = threadIdx.x & 31, ty = threadIdx.x >> 5;
  for (int i = ty; i < 32; i += 8)
    t[i][tx] = Vtmp[((size_t)bh*NN + n0+i)*DHH + d0 + tx];
  __syncthreads();
  for (int i = ty; i < 32; i += 8)
    Vt[((size_t)bh*DHH + d0+i)*NN + n0 + tx] = t[tx][i];
}

// ---------------- MFMA flash attention (bf16, swapped QK^T, 32x32x16) ------
// grid: bh(16) x qblk(16); block 256 = 4 waves x 32 q-rows. KV tiles of 64.
#define CROW(r) (((r)&3) + 8*((r)>>2) + 4*hi)
#define BUILD_PA(dst, vec, basei) { \
  int a1_ = cvtpk(vec[basei+0], vec[basei+1]); \
  int b1_ = cvtpk(vec[basei+4], vec[basei+5]); \
  asm("v_permlane32_swap_b32 %0, %1" : "+v"(a1_), "+v"(b1_)); \
  int a2_ = cvtpk(vec[basei+2], vec[basei+3]); \
  int b2_ = cvtpk(vec[basei+6], vec[basei+7]); \
  asm("v_permlane32_swap_b32 %0, %1" : "+v"(a2_), "+v"(b2_)); \
  S8I4 u_; u_.i = (int4v){a1_, a2_, b1_, b2_}; dst = u_.s; }

__global__ __launch_bounds__(256) void attn_mfma_k(
    const u16* __restrict__ Qg, const u16* __restrict__ Kg,
    const u16* __restrict__ Vtg, u16* __restrict__ AO){
  __shared__ u16 Ks[2][64*128];   // 64 rows x 256B (12 real 16B slots + 4 pad), XOR-swizzled
  __shared__ u16 Vs[2][96*64];    // 96 rows x 128B (8 slots), XOR-swizzled
  __shared__ float smc[4][32];
  const int bh = blockIdx.x >> 4;
  const int qblk = blockIdx.x & 15;
  const int b = bh >> 3, h = bh & 7;
  const int tid = threadIdx.x;
  const int w = tid >> 6, l = tid & 63;
  const int hi = l >> 5, li = l & 31;
  const int q0w = qblk*128 + w*32;

  // Q fragments (6 k-steps of 16 d), B-operand layout: lane holds Q[li][ks*16+hi*8 ..+7]
  short8 qf[6];
  {
    const u16* qrow = Qg + ((size_t)bh*NN + q0w + li)*DHH;
    #pragma unroll
    for (int ks = 0; ks < 6; ++ks)
      qf[ks] = *(const short8*)(qrow + ks*16 + hi*8);
  }

  f32x16 o0, o1, o2;
  #pragma unroll
  for (int r = 0; r < 16; ++r){ o0[r]=0.f; o1[r]=0.f; o2[r]=0.f; }
  float mrun = -1e30f, lrun = 0.f;

  // prologue: stage tile 0
  {
    #pragma unroll
    for (int it = 0; it < 3; ++it){
      const int s = tid + it*256;
      const int krow = s/12, ksl = s%12;
      short8 kv = *(const short8*)(Kg + ((size_t)bh*NN + krow)*DHH + ksl*8);
      *(short8*)((char*)&Ks[0][0] + krow*256 + (((ksl ^ (krow&7)))<<4)) = kv;
      const int vrow = s >> 3, vsl = s & 7;
      short8 vv = *(const short8*)(Vtg + ((size_t)bh*DHH + vrow)*NN + vsl*8);
      *(short8*)((char*)&Vs[0][0] + vrow*128 + (((vsl ^ (vrow&7)))<<4)) = vv;
    }
  }
  __syncthreads();

  const int NT = NN/64;
  for (int t = 0; t < NT; ++t){
    const int cur = t & 1;
    // issue next-tile global loads early (T14 split)
    short8 kst[3], vst[3];
    if (t + 1 < NT){
      const int kv0 = (t+1)*64;
      #pragma unroll
      for (int it = 0; it < 3; ++it){
        const int s = tid + it*256;
        const int krow = s/12, ksl = s%12;
        kst[it] = *(const short8*)(Kg + ((size_t)bh*NN + kv0 + krow)*DHH + ksl*8);
        const int vrow = s >> 3, vsl = s & 7;
        vst[it] = *(const short8*)(Vtg + ((size_t)bh*DHH + vrow)*NN + kv0 + vsl*8);
      }
    }
    // S^T tiles: mfma(A=K, B=Q) -> lane holds S^T[j=CROW][i=li]
    f32x16 s0, s1;
    #pragma unroll
    for (int r = 0; r < 16; ++r){ s0[r]=0.f; s1[r]=0.f; }
    #pragma unroll
    for (int ks = 0; ks < 6; ++ks){
      const int sl = ks*2 + hi;
      short8 kf0 = *(const short8*)((const char*)&Ks[cur][0] + li*256        + ((sl ^ (li&7))<<4));
      short8 kf1 = *(const short8*)((const char*)&Ks[cur][0] + (32+li)*256   + ((sl ^ ((32+li)&7))<<4));
      s0 = __builtin_amdgcn_mfma_f32_32x32x16_bf16(kf0, qf[ks], s0, 0, 0, 0);
      s1 = __builtin_amdgcn_mfma_f32_32x32x16_bf16(kf1, qf[ks], s1, 0, 0, 0);
    }
    // online softmax (row = query i = li; both hi halves combine via shfl_xor 32)
    float tm = -1e30f;
    #pragma unroll
    for (int r = 0; r < 16; ++r) tm = fmaxf(tm, fmaxf(s0[r], s1[r]));
    tm = fmaxf(tm, __shfl_xor(tm, 32));
    const float mn = fmaxf(mrun, tm);
    const float c = __expf(mrun - mn);
    mrun = mn;
    float ps = 0.f;
    #pragma unroll
    for (int r = 0; r < 16; ++r){
      float pa = __expf(s0[r] - mn);
      float pb = __expf(s1[r] - mn);
      s0[r] = pa; s1[r] = pb; ps += pa + pb;
    }
    ps += __shfl_xor(ps, 32);
    lrun = lrun * c + ps;
    if (l < 32) smc[w][l] = c;
    __builtin_amdgcn_s_waitcnt(0); // lgkm drain for same-wave LDS RAW (cheap, safe)
    #pragma unroll
    for (int r = 0; r < 16; ++r){
      const float cr = smc[w][CROW(r)];
      o0[r] *= cr; o1[r] *= cr; o2[r] *= cr;
    }
    // P fragments for PV (A-operand): 4 k-steps of 16 keys
    short8 pa0, pa1, pa2, pa3;
    BUILD_PA(pa0, s0, 0); BUILD_PA(pa1, s0, 8);
    BUILD_PA(pa2, s1, 0); BUILD_PA(pa3, s1, 8);
    // PV: O[i][d] += P[i][j] V[j][d];  B from Vt_s (lane: Vt[dt*32+li][ks*16+hi*8 ..])
    #pragma unroll
    for (int dt = 0; dt < 3; ++dt){
      const int drow = dt*32 + li;
      const char* vb_base = (const char*)&Vs[cur][0] + drow*128;
      f32x16* op = (dt==0)? &o0 : (dt==1)? &o1 : &o2;
      {
        short8 vb = *(const short8*)(vb_base + (((0*2+hi) ^ (drow&7))<<4));
        *op = __builtin_amdgcn_mfma_f32_32x32x16_bf16(pa0, vb, *op, 0, 0, 0);
      }
      {
        short8 vb = *(const short8*)(vb_base + (((1*2+hi) ^ (drow&7))<<4));
        *op = __builtin_amdgcn_mfma_f32_32x32x16_bf16(pa1, vb, *op, 0, 0, 0);
      }
      {
        short8 vb = *(const short8*)(vb_base + (((2*2+hi) ^ (drow&7))<<4));
        *op = __builtin_amdgcn_mfma_f32_32x32x16_bf16(pa2, vb, *op, 0, 0, 0);
      }
      {
        short8 vb = *(const short8*)(vb_base + (((3*2+hi) ^ (drow&7))<<4));
        *op = __builtin_amdgcn_mfma_f32_32x32x16_bf16(pa3, vb, *op, 0, 0, 0);
      }
    }
    __syncthreads();   // A: all waves done reading buf[cur]
    if (t + 1 < NT){
      #pragma unroll
      for (int it = 0; it < 3; ++it){
        const int s = tid + it*256;
        const int krow = s/12, ksl = s%12;
        *(short8*)((char*)&Ks[cur^1][0] + krow*256 + ((ksl ^ (krow&7))<<4)) = kst[it];
        const int vrow = s >> 3, vsl = s & 7;
        *(short8*)((char*)&Vs[cur^1][0] + vrow*128 + ((vsl ^ (vrow&7))<<4)) = vst[it];
      }
      __syncthreads(); // B: staged tile visible before next iteration reads
    }
  }
  // epilogue
  const float linv = 1.f / lrun;
  if (l < 32) smc[w][l] = linv;
  __builtin_amdgcn_s_waitcnt(0);
  #pragma unroll
  for (int r = 0; r < 16; ++r){
    const float lr = smc[w][CROW(r)];
    const int n = q0w + CROW(r);
    u16* dst = AO + ((size_t)b*NN + n)*DIMM + h*DHH + li;
    dst[0]  = f2b(o0[r]*lr);
    dst[32] = f2b(o1[r]*lr);
    dst[64] = f2b(o2[r]*lr);
  }
}

// ---------------- gated residual / final add (fp32) ----------------
__global__ __launch_bounds__(256) void residual_k(
    const float* __restrict__ x, const float* __restrict__ P,
    const float* __restrict__ mod, int cg, int stream, float* __restrict__ out){
  const int idx = blockIdx.x * 256 + threadIdx.x;
  const int d = idx % DIMM;
  const int bt = idx / DIMM;
  const int b = bt >> 10, t = bt & 1023;
  const int prow = b*NN + stream*TT + t;
  float gv = mod[(size_t)b*9216 + (size_t)cg*768 + d];
  out[idx] = x[idx] + P[(size_t)prow*DIMM + d] * gv;
}

__global__ __launch_bounds__(256) void final_add_k(
    const float* __restrict__ Mx, const float* __restrict__ mod, int cg,
    float* __restrict__ out){
  const int idx = blockIdx.x * 256 + threadIdx.x;
  const int d = idx % DIMM;
  const int b = (idx / DIMM) >> 10;
  float gv = mod[(size_t)b*9216 + (size_t)cg*768 + d];
  out[idx] += Mx[idx] * gv;
}

// ---------------- workspace layout (bytes) ----------------
static constexpr size_t W_QKV1T = 0;                         // 2304*768*2
static constexpr size_t W_QKV2T = W_QKV1T + 3538944;
static constexpr size_t W_OUTT  = W_QKV2T + 3538944;         // 768*768*2
static constexpr size_t W_M1W1T = W_OUTT  + 1179648;         // 3072*768*2
static constexpr size_t W_M1W2T = W_M1W1T + 4718592;
static constexpr size_t W_M2W1T = W_M1W2T + 4718592;
static constexpr size_t W_M2W2T = W_M2W1T + 4718592;
static constexpr size_t O_MODH  = W_M2W2T + 4718592;         // 1024 f
static constexpr size_t O_MODB  = O_MODH + 4096;             // 18432 f
static constexpr size_t DYN     = O_MODB + 73728;            // = 27,209,728
static constexpr size_t O_XM1   = DYN;                       // 2048*768*2
static constexpr size_t O_XM2   = O_XM1 + 3145728;
static constexpr size_t O_QKV1  = O_XM2 + 3145728;           // 2048*2304*2
static constexpr size_t O_QKV2  = O_QKV1 + 9437184;
static constexpr size_t O_QB    = O_QKV2 + 9437184;          // 16*2048*96*2
static constexpr size_t O_KB    = O_QB + 6291456;
static constexpr size_t O_VTMP  = O_KB + 6291456;
static constexpr size_t O_PF    = O_VTMP + 6291456;          // 4096*768*4
// reuse:
static constexpr size_t O_VT    = O_QKV1;                    // after build_qkv
static constexpr size_t O_AO    = O_QKV2;                    // after build_qkv
static constexpr size_t O_H1    = O_QB;                      // after attn (Q+K slots)
static constexpr size_t O_H2    = O_PF;                      // after residual
static constexpr size_t O_M1    = O_VTMP;                    // after vtrans
static constexpr size_t O_M2    = O_QKV2;                    // after out-proj (AO slot)

extern "C" void kernel_launch(void* const* d_in, const int* in_sizes, int n_in,
                              void* d_out, int out_size, void* d_ws, size_t ws_size,
                              hipStream_t stream){
  const float* x_s1   = (const float*)d_in[0];
  const float* x_s2   = (const float*)d_in[1];
  const float* p_emb  = (const float*)d_in[2];
  const float* mod_w1 = (const float*)d_in[3];
  const float* mod_b1 = (const float*)d_in[4];
  const float* mod_w2 = (const float*)d_in[5];
  const float* mod_b2 = (const float*)d_in[6];
  const float* n11_w  = (const float*)d_in[7];
  const float* n12_w  = (const float*)d_in[8];
  const float* qkv_w  = (const float*)d_in[9];
  const float* qkv_b  = (const float*)d_in[10];
  const float* qkv2_w = (const float*)d_in[11];
  const float* qkv2_b = (const float*)d_in[12];
  const float* qk_sc  = (const float*)d_in[13];
  const float* out_w  = (const float*)d_in[14];
  const float* out_b  = (const float*)d_in[15];
  const float* n21_w  = (const float*)d_in[16];
  const float* n22_w  = (const float*)d_in[17];
  const float* m1w1   = (const float*)d_in[18];
  const float* m1b1   = (const float*)d_in[19];
  const float* m1w2   = (const float*)d_in[20];
  const float* m1b2   = (const float*)d_in[21];
  const float* m2w1   = (const float*)d_in[22];
  const float* m2b1   = (const float*)d_in[23];
  const float* m2w2   = (const float*)d_in[24];
  const float* m2b2   = (const float*)d_in[25];

  char* ws = (char*)d_ws;
  u16* qkv1t = (u16*)(ws + W_QKV1T);
  u16* qkv2t = (u16*)(ws + W_QKV2T);
  u16* outt  = (u16*)(ws + W_OUTT);
  u16* w11t  = (u16*)(ws + W_M1W1T);
  u16* w12t  = (u16*)(ws + W_M1W2T);
  u16* w21t  = (u16*)(ws + W_M2W1T);
  u16* w22t  = (u16*)(ws + W_M2W2T);
  float* h2b  = (float*)(ws + O_MODH);
  float* modb = (float*)(ws + O_MODB);
  u16* xm1  = (u16*)(ws + O_XM1);
  u16* xm2  = (u16*)(ws + O_XM2);
  u16* qkv1 = (u16*)(ws + O_QKV1);
  u16* qkv2 = (u16*)(ws + O_QKV2);
  u16* Qb   = (u16*)(ws + O_QB);
  u16* Kb   = (u16*)(ws + O_KB);
  u16* Vtmp = (u16*)(ws + O_VTMP);
  u16* Vt   = (u16*)(ws + O_VT);
  u16* AO   = (u16*)(ws + O_AO);
  float* Pf = (float*)(ws + O_PF);
  u16* H1   = (u16*)(ws + O_H1);
  u16* H2   = (u16*)(ws + O_H2);
  float* M1 = (float*)(ws + O_M1);
  float* M2 = (float*)(ws + O_M2);

  float* out0 = (float*)d_out;
  float* out1 = out0 + (size_t)BB*TT*DIMM;

  // weight conversion (bf16 + transpose)  W[K][N] -> Wt[N][K]
  wt_k<<<dim3(2304/32, 768/32), 256, 0, stream>>>(qkv_w,  qkv1t, 768, 2304);
  wt_k<<<dim3(2304/32, 768/32), 256, 0, stream>>>(qkv2_w, qkv2t, 768, 2304);
  wt_k<<<dim3(768/32, 768/32),  256, 0, stream>>>(out_w,  outt,  768, 768);
  wt_k<<<dim3(3072/32, 768/32), 256, 0, stream>>>(m1w1,   w11t,  768, 3072);
  wt_k<<<dim3(768/32, 3072/32), 256, 0, stream>>>(m1w2,   w12t,  3072, 768);
  wt_k<<<dim3(3072/32, 768/32), 256, 0, stream>>>(m2w1,   w21t,  768, 3072);
  wt_k<<<dim3(768/32, 3072/32), 256, 0, stream>>>(m2w2,   w22t,  3072, 768);

  // modulation MLP
  mod_stage1_k<<<4, 256, 0, stream>>>(p_emb, mod_w1, mod_b1, h2b);
  mod_stage2_k<<<72, 256, 0, stream>>>(h2b, mod_w2, mod_b2, modb);

  // pre-attention norms -> bf16
  rmsnorm_mod_k<<<BB*TT, 256, 0, stream>>>(x_s1, n11_w, modb, 0, 1, xm1);
  rmsnorm_mod_k<<<BB*TT, 256, 0, stream>>>(x_s2, n12_w, modb, 3, 4, xm2);

  // QKV GEMMs (dual): [2048,768]@[768,2304] -> bf16
  gemm_bf16_k<0,1,1><<<dim3(18, 16, 2), 256, 0, stream>>>(
      xm1, qkv1t, qkv_b, qkv1, xm2, qkv2t, qkv2_b, qkv2, 2048, 2304, 768);

  // heads + RoPE + l2norm*scale -> Q,K,Vtmp bf16
  build_qkv_k<<<(BB*NHEADS*NN)/4, 256, 0, stream>>>(qkv1, qkv2, qk_sc, Qb, Kb, Vtmp);

  // V transpose -> Vt[bh][96][2048]
  vtrans_k<<<dim3(NN/32, DHH/32, 16), 256, 0, stream>>>(Vtmp, Vt);

  // MFMA attention -> AO bf16 [B*N, 768]
  attn_mfma_k<<<16*16, 256, 0, stream>>>(Qb, Kb, Vt, AO);

  // out projection: [4096,768]@[768,768] -> fp32
  gemm_bf16_k<0,0,0><<<dim3(6, 32, 1), 256, 0, stream>>>(
      AO, outt, out_b, Pf, AO, outt, out_b, Pf, 4096, 768, 768);

  // gated residual -> d_out
  residual_k<<<6144, 256, 0, stream>>>(x_s1, Pf, modb, 2, 0, out0);
  residual_k<<<6144, 256, 0, stream>>>(x_s2, Pf, modb, 5, 1, out1);

  // post-attention norms -> bf16 (reuse xm slots)
  rmsnorm_mod_k<<<BB*TT, 256, 0, stream>>>(out0, n21_w, modb, 6, 7, xm1);
  rmsnorm_mod_k<<<BB*TT, 256, 0, stream>>>(out1, n22_w, modb, 9, 10, xm2);

  // MLP up (dual, GELU) -> bf16
  gemm_bf16_k<1,1,1><<<dim3(24, 16, 2), 256, 0, stream>>>(
      xm1, w11t, m1b1, H1, xm2, w21t, m2b1, H2, 2048, 3072, 768);
  // MLP down 1 -> fp32 (H2 overlaps Pf slot; Pf already consumed by residuals)
  gemm_bf16_k<0,0,0><<<dim3(6, 16, 1), 256, 0, stream>>>(
      H1, w12t, m1b2, M1, H1, w12t, m1b2, M1, 2048, 768, 3072);
  gemm_bf16_k<0,0,0><<<dim3(6, 16, 1), 256, 0, stream>>>(
      H2, w22t, m2b2, M2, H2, w22t, m2b2, M2, 2048, 768, 3072);

  // final gated adds
  final_add_k<<<6144, 256, 0, stream>>>(M1, modb, 8, out0);
  final_add_k<<<6144, 256, 0, stream>>>(M2, modb, 11, out1);
}

// Round 3
// 309.608 us; speedup vs baseline: 14.8757x; 1.3258x over previous
//
#include <hip/hip_runtime.h>
#include <hip/hip_bf16.h>
#include <cstdint>
#include <math.h>

#define BB 2
#define TT 1024
#define DIMM 768
#define NHEADS 8
#define DHH 96
#define MLPD 3072
#define NN 2048   // 2*T

typedef unsigned short u16;
using short8 = __attribute__((ext_vector_type(8))) short;
using f32x4  = __attribute__((ext_vector_type(4))) float;
using f32x16 = __attribute__((ext_vector_type(16))) float;
using int4v  = __attribute__((ext_vector_type(4))) int;
union S8I4 { int4v i; short8 s; };

static constexpr float kEps = 1e-6f;

__device__ __forceinline__ float siluf(float x){ return x / (1.f + expf(-x)); }
__device__ __forceinline__ float geluf(float x){ return 0.5f*x*(1.f + erff(x*0.7071067811865475f)); }
__device__ __forceinline__ float bf16_rne(float x){
  uint32_t u = __float_as_uint(x);
  u = (u + 0x7fffu + ((u >> 16) & 1u)) & 0xffff0000u;
  return __uint_as_float(u);
}
__device__ __forceinline__ u16 f2b(float x){
  uint32_t u = __float_as_uint(x);
  return (u16)((u + 0x7fffu + ((u >> 16) & 1u)) >> 16);
}
__device__ __forceinline__ float b2f(u16 b){
  return __uint_as_float(((uint32_t)b) << 16);
}
__device__ __forceinline__ int cvtpk(float lo, float hi){
  int d; asm("v_cvt_pk_bf16_f32 %0, %1, %2" : "=v"(d) : "v"(lo), "v"(hi)); return d;
}
__device__ __forceinline__ void gload16(const void* g, void* l){
  __builtin_amdgcn_global_load_lds((const __attribute__((address_space(1))) unsigned int*)g,
                                   (__attribute__((address_space(3))) unsigned int*)l, 16, 0, 0);
}

// ---------------- modulation MLP (fp32, tiny) ----------------
__global__ __launch_bounds__(256) void mod_stage1_k(
    const float* __restrict__ p_emb, const float* __restrict__ w1,
    const float* __restrict__ b1, float* __restrict__ h2){
  __shared__ float sp[1024];
  const int b = blockIdx.x >> 1;
  const int obase = (blockIdx.x & 1) * 256;
  for (int i = threadIdx.x; i < 1024; i += 256)
    sp[i] = siluf(p_emb[b*1024 + i]);
  __syncthreads();
  const int o = obase + threadIdx.x;
  float acc = 0.f;
  for (int j = 0; j < 1024; ++j) acc += sp[j] * w1[j*512 + o];
  h2[b*512 + o] = siluf(acc + b1[o]);
}

__global__ __launch_bounds__(256) void mod_stage2_k(
    const float* __restrict__ h2, const float* __restrict__ w2,
    const float* __restrict__ b2, float* __restrict__ mod){
  __shared__ float sh[512];
  const int b = blockIdx.x / 36;
  const int obase = (blockIdx.x % 36) * 256;
  for (int i = threadIdx.x; i < 512; i += 256)
    sh[i] = h2[b*512 + i];
  __syncthreads();
  const int o = obase + threadIdx.x;
  float acc = 0.f;
  for (int j = 0; j < 512; ++j) acc += sh[j] * w2[j*9216 + o];
  mod[b*9216 + o] = acc + b2[o];
}

// ------------- fused weight convert+transpose (all 7 weights, 1 launch) -----
// W[K][N] f32 -> Wt[N][K] bf16
__global__ __launch_bounds__(256) void wt_all_k(
    const float* __restrict__ s0, u16* __restrict__ d0,
    const float* __restrict__ s1, u16* __restrict__ d1,
    const float* __restrict__ s2, u16* __restrict__ d2,
    const float* __restrict__ s3, u16* __restrict__ d3,
    const float* __restrict__ s4, u16* __restrict__ d4,
    const float* __restrict__ s5, u16* __restrict__ d5,
    const float* __restrict__ s6, u16* __restrict__ d6){
  const int bid = blockIdx.x;
  const float* S; u16* D; int K, N, lid;
  if      (bid < 1728) { S=s0; D=d0; K=768;  N=2304; lid=bid; }
  else if (bid < 3456) { S=s1; D=d1; K=768;  N=2304; lid=bid-1728; }
  else if (bid < 4032) { S=s2; D=d2; K=768;  N=768;  lid=bid-3456; }
  else if (bid < 6336) { S=s3; D=d3; K=768;  N=3072; lid=bid-4032; }
  else if (bid < 8640) { S=s4; D=d4; K=3072; N=768;  lid=bid-6336; }
  else if (bid < 10944){ S=s5; D=d5; K=768;  N=3072; lid=bid-8640; }
  else                 { S=s6; D=d6; K=3072; N=768;  lid=bid-10944; }
  const int nx = N >> 5;
  const int k0 = (lid / nx) * 32, n0 = (lid % nx) * 32;
  __shared__ float t[32][33];
  const int tx = threadIdx.x & 31, ty = threadIdx.x >> 5;
  for (int i = ty; i < 32; i += 8)
    t[i][tx] = S[(size_t)(k0+i)*N + n0 + tx];
  __syncthreads();
  for (int i = ty; i < 32; i += 8)
    D[(size_t)(n0+i)*K + k0 + tx] = f2b(t[tx][i]);
}

// ---------------- RMSNorm + modulation -> bf16 (both streams, 1 launch) ----
__global__ __launch_bounds__(256) void rmsnorm2_k(
    const float* __restrict__ x0, const float* __restrict__ w0, int cs0, int ch0, u16* __restrict__ o0,
    const float* __restrict__ x1, const float* __restrict__ w1, int cs1, int ch1, u16* __restrict__ o1,
    const float* __restrict__ mod){
  const int rowg = blockIdx.x;
  const int s = rowg >> 11;
  const int row = rowg & 2047;
  const float* x = s ? x1 : x0;
  const float* w = s ? w1 : w0;
  const int cs = s ? cs1 : cs0, ch = s ? ch1 : ch0;
  u16* out = s ? o1 : o0;
  const int b = row >> 10;
  const int tid = threadIdx.x;
  const float* xr = x + (size_t)row * DIMM;
  float v0 = xr[tid], v1 = xr[tid + 256], v2 = xr[tid + 512];
  float ss = v0*v0 + v1*v1 + v2*v2;
  __shared__ float red[4];
  for (int m = 1; m < 64; m <<= 1) ss += __shfl_xor(ss, m, 64);
  if ((tid & 63) == 0) red[tid >> 6] = ss;
  __syncthreads();
  float tot = red[0] + red[1] + red[2] + red[3];
  float rms = rsqrtf(tot * (1.f/768.f) + kEps);
  const float* ms = mod + (size_t)b*9216 + (size_t)cs*768;
  const float* mh = mod + (size_t)b*9216 + (size_t)ch*768;
  u16* orow = out + (size_t)row * DIMM;
  orow[tid]       = f2b(v0*rms*w[tid]      *(1.f+ms[tid])       + mh[tid]);
  orow[tid + 256] = f2b(v1*rms*w[tid+256]  *(1.f+ms[tid+256])   + mh[tid+256]);
  orow[tid + 512] = f2b(v2*rms*w[tid+512]  *(1.f+ms[tid+512])   + mh[tid+512]);
}

// ---------------- bf16 MFMA GEMM with fused epilogues ----------------------
// A[M,K] bf16 row-major, Bt[N,K] bf16 row-major (pre-transposed weights).
// 128x128 tile, BK=32, 4 waves (2x2), each wave 64x64 via 4x4 of 16x16x32.
// EPI: 1 = bf16 store; 2 = gelu->bf16 store; 3 = out = X + (v)*gate (outproj,
// stream by row); 4 = O += v*gate (final add, O/cg by z).
template<int EPI, int DUAL>
__global__ __launch_bounds__(256) void gemm_bf16_k(
    const u16* __restrict__ A0, const u16* __restrict__ Bt0,
    const float* __restrict__ bias0, void* __restrict__ C0,
    const u16* __restrict__ A1, const u16* __restrict__ Bt1,
    const float* __restrict__ bias1, void* __restrict__ C1,
    const float* __restrict__ mod, const float* __restrict__ X0,
    const float* __restrict__ X1, float* __restrict__ O0,
    float* __restrict__ O1, int cg0, int cg1,
    int M, int N, int K){
  __shared__ u16 As[2][128*32];
  __shared__ u16 Bs[2][128*32];
  const int z = DUAL ? blockIdx.z : 0;
  const u16* A      = z ? A1 : A0;
  const u16* Bt     = z ? Bt1 : Bt0;
  const float* bias = z ? bias1 : bias0;
  void* C           = z ? C1 : C0;
  const int tid = threadIdx.x;
  const int w = tid >> 6, l = tid & 63;
  const int m0 = blockIdx.y*128, n0 = blockIdx.x*128;
  const int wr = w >> 1, wc = w & 1;
  const int la = l & 15, hi4 = l >> 4;
  f32x4 acc[4][4] = {};
  const int nk = K >> 5;
  #pragma unroll
  for (int it = 0; it < 2; ++it){
    const int sb = w*128 + it*64;
    const int s = sb + l;
    const int row = s >> 2, sl = s & 3;
    gload16(A  + (size_t)(m0+row)*K + sl*8, &As[0][sb*8]);
    gload16(Bt + (size_t)(n0+row)*K + sl*8, &Bs[0][sb*8]);
  }
  __syncthreads();
  for (int kt = 0; kt < nk; ++kt){
    const int cur = kt & 1;
    if (kt + 1 < nk){
      const int k0n = (kt+1) << 5;
      #pragma unroll
      for (int it = 0; it < 2; ++it){
        const int sb = w*128 + it*64;
        const int s = sb + l;
        const int row = s >> 2, sl = s & 3;
        gload16(A  + (size_t)(m0+row)*K + k0n + sl*8, &As[cur^1][sb*8]);
        gload16(Bt + (size_t)(n0+row)*K + k0n + sl*8, &Bs[cur^1][sb*8]);
      }
    }
    short8 af[4], bf[4];
    #pragma unroll
    for (int mi = 0; mi < 4; ++mi)
      af[mi] = *(const short8*)((const char*)&As[cur][0] + (wr*64 + mi*16 + la)*64 + hi4*16);
    #pragma unroll
    for (int ni = 0; ni < 4; ++ni)
      bf[ni] = *(const short8*)((const char*)&Bs[cur][0] + (wc*64 + ni*16 + la)*64 + hi4*16);
    #pragma unroll
    for (int mi = 0; mi < 4; ++mi)
      #pragma unroll
      for (int ni = 0; ni < 4; ++ni)
        acc[mi][ni] = __builtin_amdgcn_mfma_f32_16x16x32_bf16(af[mi], bf[ni], acc[mi][ni], 0, 0, 0);
    __syncthreads();
  }
  // epilogue
  #pragma unroll
  for (int mi = 0; mi < 4; ++mi){
    #pragma unroll
    for (int ni = 0; ni < 4; ++ni){
      const int n = n0 + wc*64 + ni*16 + la;
      const float bv = bias[n];
      #pragma unroll
      for (int rr = 0; rr < 4; ++rr){
        const int m = m0 + wr*64 + mi*16 + hi4*4 + rr;
        float v = acc[mi][ni][rr] + bv;
        if constexpr (EPI == 2) v = geluf(v);
        if constexpr (EPI == 1 || EPI == 2){
          ((u16*)C)[(size_t)m*N + n] = f2b(v);
        } else if constexpr (EPI == 3){
          const int bb = m >> 11, ss = (m >> 10) & 1, t = m & 1023;
          const float* X = ss ? X1 : X0;
          float* O = ss ? O1 : O0;
          const float g = mod[(size_t)bb*9216 + (size_t)(ss ? cg1 : cg0)*768 + n];
          const size_t oi = ((size_t)(bb*1024 + t))*768 + n;
          O[oi] = X[oi] + v*g;
        } else if constexpr (EPI == 4){
          float* O = z ? O1 : O0;
          const int cg = z ? cg1 : cg0;
          const int bb = m >> 10;
          const float g = mod[(size_t)bb*9216 + (size_t)cg*768 + n];
          O[(size_t)m*N + n] += v*g;
        }
      }
    }
  }
}

// ---------------- head split + RoPE + L2norm*scale (bf16 io) ---------------
__global__ __launch_bounds__(256) void build_qkv_k(
    const u16* __restrict__ qkv1, const u16* __restrict__ qkv2,
    const float* __restrict__ qk_scale,
    u16* __restrict__ Q, u16* __restrict__ K, u16* __restrict__ V){
  const int wid = threadIdx.x >> 6;
  const int lane = threadIdx.x & 63;
  const int row = blockIdx.x * 4 + wid;         // (b*8+h)*2048 + n
  const int n = row & 2047;
  const int h = (row >> 11) & 7;
  const int b = row >> 14;
  const u16* src = (n < TT) ? (qkv1 + ((size_t)b*TT + n) * 2304)
                            : (qkv2 + ((size_t)b*TT + (n - TT)) * 2304);
  const int col = h * DHH;
  const bool act = lane < 48;
  float q0=0,q1=0,k0=0,k1=0,v0=0,v1=0,c=1.f,s=0.f,sc0=0,sc1=0;
  if (act){
    q0 = b2f(src[col + lane]);        q1 = b2f(src[col + lane + 48]);
    k0 = b2f(src[768 + col + lane]);  k1 = b2f(src[768 + col + lane + 48]);
    v0 = b2f(src[1536 + col + lane]); v1 = b2f(src[1536 + col + lane + 48]);
    float inv = bf16_rne((float)(1.0 / pow(10000.0, (2.0 * lane) / 96.0)));
    float ang = (float)n * inv;
    c = cosf(ang); s = sinf(ang);
    sc0 = qk_scale[lane]; sc1 = qk_scale[lane + 48];
  }
  float qr0 = q0*c - q1*s, qr1 = q1*c + q0*s;
  float kr0 = k0*c - k1*s, kr1 = k1*c + k0*s;
  float ssq = qr0*qr0 + qr1*qr1;
  float ssk = kr0*kr0 + kr1*kr1;
  for (int m = 1; m < 64; m <<= 1){ ssq += __shfl_xor(ssq, m, 64); ssk += __shfl_xor(ssk, m, 64); }
  float rq = 1.f / fmaxf(sqrtf(ssq), 1e-12f);
  float rk = 1.f / fmaxf(sqrtf(ssk), 1e-12f);
  const float sscale = 0.1020620726159658f;  // 96^-0.5 folded into Q
  if (act){
    size_t base = (size_t)row * DHH;
    Q[base + lane]      = f2b(qr0*rq*sc0*sscale);  Q[base + lane + 48] = f2b(qr1*rq*sc1*sscale);
    K[base + lane]      = f2b(kr0*rk*sc0);         K[base + lane + 48] = f2b(kr1*rk*sc1);
    V[base + lane]      = f2b(v0);                 V[base + lane + 48] = f2b(v1);
  }
}

// ---------------- V transpose: Vtmp[bh][n][96] -> Vt[bh][96][2048] ----------
__global__ __launch_bounds__(256) void vtrans_k(
    const u16* __restrict__ Vtmp, u16* __restrict__ Vt){
  __shared__ u16 t[32][33];
  const int bh = blockIdx.z;
  const int n0 = blockIdx.x*32, d0 = blockIdx.y*32;
  const int tx = threadIdx.x & 31, ty = threadIdx.x >> 5;
  for (int i = ty; i < 32; i += 8)
    t[i][tx] = Vtmp[((size_t)bh*NN + n0+i)*DHH + d0 + tx];
  __syncthreads();
  for (int i = ty; i < 32; i += 8)
    Vt[((size_t)bh*DHH + d0+i)*NN + n0 + tx] = t[tx][i];
}

// ---------------- MFMA flash attention, 8 waves = 2 KV-split groups --------
// grid: bh(16) x qblk(16); block 512 = 2 groups x 4 waves x 32 q-rows.
// Fixed-max softmax: scores bounded by ||Q||*||K|| = 1.021*10.04 < 10.5.
#define CROW(r) (((r)&3) + 8*((r)>>2) + 4*hi)
#define SMAXC 10.5f
#define BUILD_PA(dst, vec, basei) { \
  int a1_ = cvtpk(vec[basei+0], vec[basei+1]); \
  int b1_ = cvtpk(vec[basei+4], vec[basei+5]); \
  asm("v_permlane32_swap_b32 %0, %1" : "+v"(a1_), "+v"(b1_)); \
  int a2_ = cvtpk(vec[basei+2], vec[basei+3]); \
  int b2_ = cvtpk(vec[basei+6], vec[basei+7]); \
  asm("v_permlane32_swap_b32 %0, %1" : "+v"(a2_), "+v"(b2_)); \
  S8I4 u_; u_.i = (int4v){a1_, a2_, b1_, b2_}; dst = u_.s; }

__global__ __launch_bounds__(512) void attn_mfma_k(
    const u16* __restrict__ Qg, const u16* __restrict__ Kg,
    const u16* __restrict__ Vtg, u16* __restrict__ AO){
  __shared__ u16 Ks[2][2][64*128];   // [group][buf]; 64 rows x 256B, XOR-swizzled
  __shared__ u16 Vs[2][2][96*64];    // [group][buf]; 96 rows x 128B, XOR-swizzled
  const int bh = blockIdx.x >> 4;
  const int qblk = blockIdx.x & 15;
  const int b = bh >> 3, h = bh & 7;
  const int tid = threadIdx.x;
  const int w = tid >> 6, l = tid & 63;
  const int g2 = w >> 2, wq = w & 3;
  const int gtid = tid & 255;
  const int hi = l >> 5, li = l & 31;
  const int q0w = qblk*128 + wq*32;
  const int kvbase = g2 * 1024;

  // Q fragments (6 k-steps of 16 d): lane holds Q[li][ks*16+hi*8 ..+7]
  short8 qf[6];
  {
    const u16* qrow = Qg + ((size_t)bh*NN + q0w + li)*DHH;
    #pragma unroll
    for (int ks = 0; ks < 6; ++ks)
      qf[ks] = *(const short8*)(qrow + ks*16 + hi*8);
  }

  f32x16 o0, o1, o2;
  #pragma unroll
  for (int r = 0; r < 16; ++r){ o0[r]=0.f; o1[r]=0.f; o2[r]=0.f; }
  float lrun = 0.f;

  // prologue: stage this group's tile 0
  {
    #pragma unroll
    for (int it = 0; it < 3; ++it){
      const int s = gtid + it*256;
      const int krow = s/12, ksl = s%12;
      short8 kv = *(const short8*)(Kg + ((size_t)bh*NN + kvbase + krow)*DHH + ksl*8);
      *(short8*)((char*)&Ks[g2][0][0] + krow*256 + ((ksl ^ (krow&7))<<4)) = kv;
      const int vrow = s >> 3, vsl = s & 7;
      short8 vv = *(const short8*)(Vtg + ((size_t)bh*DHH + vrow)*NN + kvbase + vsl*8);
      *(short8*)((char*)&Vs[g2][0][0] + vrow*128 + ((vsl ^ (vrow&7))<<4)) = vv;
    }
  }
  __syncthreads();

  const int NT2 = 16;   // 1024 keys per group / 64
  for (int t = 0; t < NT2; ++t){
    const int cur = t & 1;
    // T14: issue next-tile global loads early
    short8 kst[3], vst[3];
    if (t + 1 < NT2){
      const int kv0 = kvbase + (t+1)*64;
      #pragma unroll
      for (int it = 0; it < 3; ++it){
        const int s = gtid + it*256;
        const int krow = s/12, ksl = s%12;
        kst[it] = *(const short8*)(Kg + ((size_t)bh*NN + kv0 + krow)*DHH + ksl*8);
        const int vrow = s >> 3, vsl = s & 7;
        vst[it] = *(const short8*)(Vtg + ((size_t)bh*DHH + vrow)*NN + kv0 + vsl*8);
      }
    }
    // S^T tiles: mfma(A=K, B=Q) -> lane holds S^T[j=CROW][i=li]
    f32x16 s0, s1;
    #pragma unroll
    for (int r = 0; r < 16; ++r){ s0[r]=0.f; s1[r]=0.f; }
    #pragma unroll
    for (int ks = 0; ks < 6; ++ks){
      const int sl = ks*2 + hi;
      short8 kf0 = *(const short8*)((const char*)&Ks[g2][cur][0] + li*256      + ((sl ^ (li&7))<<4));
      short8 kf1 = *(const short8*)((const char*)&Ks[g2][cur][0] + (32+li)*256 + ((sl ^ ((32+li)&7))<<4));
      s0 = __builtin_amdgcn_mfma_f32_32x32x16_bf16(kf0, qf[ks], s0, 0, 0, 0);
      s1 = __builtin_amdgcn_mfma_f32_32x32x16_bf16(kf1, qf[ks], s1, 0, 0, 0);
    }
    // fixed-max softmax: no running max, no rescale
    float ps = 0.f;
    #pragma unroll
    for (int r = 0; r < 16; ++r){
      float pa = __expf(s0[r] - SMAXC);
      float pb = __expf(s1[r] - SMAXC);
      s0[r] = pa; s1[r] = pb; ps += pa + pb;
    }
    ps += __shfl_xor(ps, 32);
    lrun += ps;
    // P fragments for PV (A-operand)
    short8 pa0, pa1, pa2, pa3;
    BUILD_PA(pa0, s0, 0); BUILD_PA(pa1, s0, 8);
    BUILD_PA(pa2, s1, 0); BUILD_PA(pa3, s1, 8);
    // PV
    #pragma unroll
    for (int dt = 0; dt < 3; ++dt){
      const int drow = dt*32 + li;
      const char* vb_base = (const char*)&Vs[g2][cur][0] + drow*128;
      f32x16* op = (dt==0)? &o0 : (dt==1)? &o1 : &o2;
      {
        short8 vb = *(const short8*)(vb_base + (((0*2+hi) ^ (drow&7))<<4));
        *op = __builtin_amdgcn_mfma_f32_32x32x16_bf16(pa0, vb, *op, 0, 0, 0);
      }
      {
        short8 vb = *(const short8*)(vb_base + (((1*2+hi) ^ (drow&7))<<4));
        *op = __builtin_amdgcn_mfma_f32_32x32x16_bf16(pa1, vb, *op, 0, 0, 0);
      }
      {
        short8 vb = *(const short8*)(vb_base + (((2*2+hi) ^ (drow&7))<<4));
        *op = __builtin_amdgcn_mfma_f32_32x32x16_bf16(pa2, vb, *op, 0, 0, 0);
      }
      {
        short8 vb = *(const short8*)(vb_base + (((3*2+hi) ^ (drow&7))<<4));
        *op = __builtin_amdgcn_mfma_f32_32x32x16_bf16(pa3, vb, *op, 0, 0, 0);
      }
    }
    __syncthreads();   // all waves done reading buf[cur]
    if (t + 1 < NT2){
      #pragma unroll
      for (int it = 0; it < 3; ++it){
        const int s = gtid + it*256;
        const int krow = s/12, ksl = s%12;
        *(short8*)((char*)&Ks[g2][cur^1][0] + krow*256 + ((ksl ^ (krow&7))<<4)) = kst[it];
        const int vrow = s >> 3, vsl = s & 7;
        *(short8*)((char*)&Vs[g2][cur^1][0] + vrow*128 + ((vsl ^ (vrow&7))<<4)) = vst[it];
      }
      __syncthreads();
    }
  }

  // combine the two KV-halves through LDS (fixed max -> plain sums)
  float* cmb = (float*)&Ks[0][0][0];   // 4*16*3*64 f32 = 48KB (fits in Ks)
  float* cl  = (float*)&Vs[0][0][0];   // 4*32 f32
  if (g2 == 1){
    #pragma unroll
    for (int r = 0; r < 16; ++r){
      cmb[((wq*16 + r)*3 + 0)*64 + l] = o0[r];
      cmb[((wq*16 + r)*3 + 1)*64 + l] = o1[r];
      cmb[((wq*16 + r)*3 + 2)*64 + l] = o2[r];
    }
    if (l < 32) cl[wq*32 + l] = lrun;
  }
  __syncthreads();
  if (g2 == 0){
    #pragma unroll
    for (int r = 0; r < 16; ++r){
      o0[r] += cmb[((wq*16 + r)*3 + 0)*64 + l];
      o1[r] += cmb[((wq*16 + r)*3 + 1)*64 + l];
      o2[r] += cmb[((wq*16 + r)*3 + 2)*64 + l];
    }
    lrun += cl[wq*32 + li];
    const float linv = 1.f / lrun;
    #pragma unroll
    for (int r = 0; r < 16; ++r){
      const float lr = __shfl(linv, CROW(r), 64);
      const int n = q0w + CROW(r);
      u16* dst = AO + ((size_t)b*NN + n)*DIMM + h*DHH + li;
      dst[0]  = f2b(o0[r]*lr);
      dst[32] = f2b(o1[r]*lr);
      dst[64] = f2b(o2[r]*lr);
    }
  }
}

// ---------------- workspace layout (bytes) ----------------
static constexpr size_t W_QKV1T = 0;                         // 2304*768*2
static constexpr size_t W_QKV2T = W_QKV1T + 3538944;
static constexpr size_t W_OUTT  = W_QKV2T + 3538944;         // 768*768*2
static constexpr size_t W_M1W1T = W_OUTT  + 1179648;         // 3072*768*2
static constexpr size_t W_M1W2T = W_M1W1T + 4718592;
static constexpr size_t W_M2W1T = W_M1W2T + 4718592;
static constexpr size_t W_M2W2T = W_M2W1T + 4718592;
static constexpr size_t O_MODH  = W_M2W2T + 4718592;         // 1024 f
static constexpr size_t O_MODB  = O_MODH + 4096;             // 18432 f
static constexpr size_t DYN     = O_MODB + 73728;
static constexpr size_t O_XM1   = DYN;                       // 2048*768*2
static constexpr size_t O_XM2   = O_XM1 + 3145728;
static constexpr size_t O_QKV1  = O_XM2 + 3145728;           // 2048*2304*2
static constexpr size_t O_QKV2  = O_QKV1 + 9437184;
static constexpr size_t O_QB    = O_QKV2 + 9437184;          // 16*2048*96*2
static constexpr size_t O_KB    = O_QB + 6291456;
static constexpr size_t O_VTMP  = O_KB + 6291456;
static constexpr size_t O_PF    = O_VTMP + 6291456;          // 12,582,912
// reuse:
static constexpr size_t O_VT    = O_QKV1;                    // after build_qkv
static constexpr size_t O_AO    = O_QKV2;                    // after build_qkv
static constexpr size_t O_H1    = O_QB;                      // after attn (Q+K slots)
static constexpr size_t O_H2    = O_PF;

extern "C" void kernel_launch(void* const* d_in, const int* in_sizes, int n_in,
                              void* d_out, int out_size, void* d_ws, size_t ws_size,
                              hipStream_t stream){
  const float* x_s1   = (const float*)d_in[0];
  const float* x_s2   = (const float*)d_in[1];
  const float* p_emb  = (const float*)d_in[2];
  const float* mod_w1 = (const float*)d_in[3];
  const float* mod_b1 = (const float*)d_in[4];
  const float* mod_w2 = (const float*)d_in[5];
  const float* mod_b2 = (const float*)d_in[6];
  const float* n11_w  = (const float*)d_in[7];
  const float* n12_w  = (const float*)d_in[8];
  const float* qkv_w  = (const float*)d_in[9];
  const float* qkv_b  = (const float*)d_in[10];
  const float* qkv2_w = (const float*)d_in[11];
  const float* qkv2_b = (const float*)d_in[12];
  const float* qk_sc  = (const float*)d_in[13];
  const float* out_w  = (const float*)d_in[14];
  const float* out_b  = (const float*)d_in[15];
  const float* n21_w  = (const float*)d_in[16];
  const float* n22_w  = (const float*)d_in[17];
  const float* m1w1   = (const float*)d_in[18];
  const float* m1b1   = (const float*)d_in[19];
  const float* m1w2   = (const float*)d_in[20];
  const float* m1b2   = (const float*)d_in[21];
  const float* m2w1   = (const float*)d_in[22];
  const float* m2b1   = (const float*)d_in[23];
  const float* m2w2   = (const float*)d_in[24];
  const float* m2b2   = (const float*)d_in[25];

  char* ws = (char*)d_ws;
  u16* qkv1t = (u16*)(ws + W_QKV1T);
  u16* qkv2t = (u16*)(ws + W_QKV2T);
  u16* outt  = (u16*)(ws + W_OUTT);
  u16* w11t  = (u16*)(ws + W_M1W1T);
  u16* w12t  = (u16*)(ws + W_M1W2T);
  u16* w21t  = (u16*)(ws + W_M2W1T);
  u16* w22t  = (u16*)(ws + W_M2W2T);
  float* h2b  = (float*)(ws + O_MODH);
  float* modb = (float*)(ws + O_MODB);
  u16* xm1  = (u16*)(ws + O_XM1);
  u16* xm2  = (u16*)(ws + O_XM2);
  u16* qkv1 = (u16*)(ws + O_QKV1);
  u16* qkv2 = (u16*)(ws + O_QKV2);
  u16* Qb   = (u16*)(ws + O_QB);
  u16* Kb   = (u16*)(ws + O_KB);
  u16* Vtmp = (u16*)(ws + O_VTMP);
  u16* Vt   = (u16*)(ws + O_VT);
  u16* AO   = (u16*)(ws + O_AO);
  u16* H1   = (u16*)(ws + O_H1);
  u16* H2   = (u16*)(ws + O_H2);

  float* out0 = (float*)d_out;
  float* out1 = out0 + (size_t)BB*TT*DIMM;

  // all weight conversions in one launch
  wt_all_k<<<13248, 256, 0, stream>>>(qkv_w, qkv1t, qkv2_w, qkv2t, out_w, outt,
                                      m1w1, w11t, m1w2, w12t, m2w1, w21t, m2w2, w22t);

  // modulation MLP
  mod_stage1_k<<<4, 256, 0, stream>>>(p_emb, mod_w1, mod_b1, h2b);
  mod_stage2_k<<<72, 256, 0, stream>>>(h2b, mod_w2, mod_b2, modb);

  // pre-attention norms (both streams) -> bf16
  rmsnorm2_k<<<2*BB*TT, 256, 0, stream>>>(x_s1, n11_w, 0, 1, xm1,
                                          x_s2, n12_w, 3, 4, xm2, modb);

  // QKV GEMMs (dual): [2048,768]@[768,2304] -> bf16
  gemm_bf16_k<1,1><<<dim3(18, 16, 2), 256, 0, stream>>>(
      xm1, qkv1t, qkv_b, qkv1, xm2, qkv2t, qkv2_b, qkv2,
      nullptr, nullptr, nullptr, nullptr, nullptr, 0, 0, 2048, 2304, 768);

  // heads + RoPE + l2norm*scale -> Q,K,Vtmp bf16
  build_qkv_k<<<(BB*NHEADS*NN)/4, 256, 0, stream>>>(qkv1, qkv2, qk_sc, Qb, Kb, Vtmp);

  // V transpose -> Vt[bh][96][2048]
  vtrans_k<<<dim3(NN/32, DHH/32, 16), 256, 0, stream>>>(Vtmp, Vt);

  // MFMA attention (8 waves, KV-split) -> AO bf16 [B*N, 768]
  attn_mfma_k<<<16*16, 512, 0, stream>>>(Qb, Kb, Vt, AO);

  // out projection + fused gated residual -> d_out
  gemm_bf16_k<3,0><<<dim3(6, 32, 1), 256, 0, stream>>>(
      AO, outt, out_b, nullptr, AO, outt, out_b, nullptr,
      modb, x_s1, x_s2, out0, out1, 2, 5, 4096, 768, 768);

  // post-attention norms (both streams) -> bf16
  rmsnorm2_k<<<2*BB*TT, 256, 0, stream>>>(out0, n21_w, 6, 7, xm1,
                                          out1, n22_w, 9, 10, xm2, modb);

  // MLP up (dual, GELU) -> bf16
  gemm_bf16_k<2,1><<<dim3(24, 16, 2), 256, 0, stream>>>(
      xm1, w11t, m1b1, H1, xm2, w21t, m2b1, H2,
      nullptr, nullptr, nullptr, nullptr, nullptr, 0, 0, 2048, 3072, 768);

  // MLP down (dual) + fused final gated add (RMW d_out)
  gemm_bf16_k<4,1><<<dim3(6, 16, 2), 256, 0, stream>>>(
      H1, w12t, m1b2, nullptr, H2, w22t, m2b2, nullptr,
      modb, nullptr, nullptr, out0, out1, 8, 11, 2048, 768, 3072);
}

// Round 4
// 280.012 us; speedup vs baseline: 16.4480x; 1.1057x over previous
//
#include <hip/hip_runtime.h>
#include <hip/hip_bf16.h>
#include <cstdint>
#include <math.h>

#define BB 2
#define TT 1024
#define DIMM 768
#define NHEADS 8
#define DHH 96
#define MLPD 3072
#define NN 2048   // 2*T

typedef unsigned short u16;
using short8 = __attribute__((ext_vector_type(8))) short;
using f32x4  = __attribute__((ext_vector_type(4))) float;
using f32x16 = __attribute__((ext_vector_type(16))) float;
using int4v  = __attribute__((ext_vector_type(4))) int;
union S8I4 { int4v i; short8 s; };

static constexpr float kEps = 1e-6f;

__device__ __forceinline__ float siluf(float x){ return x / (1.f + expf(-x)); }
__device__ __forceinline__ float geluf(float x){ return 0.5f*x*(1.f + erff(x*0.7071067811865475f)); }
__device__ __forceinline__ float bf16_rne(float x){
  uint32_t u = __float_as_uint(x);
  u = (u + 0x7fffu + ((u >> 16) & 1u)) & 0xffff0000u;
  return __uint_as_float(u);
}
__device__ __forceinline__ u16 f2b(float x){
  uint32_t u = __float_as_uint(x);
  return (u16)((u + 0x7fffu + ((u >> 16) & 1u)) >> 16);
}
__device__ __forceinline__ float b2f(u16 b){
  return __uint_as_float(((uint32_t)b) << 16);
}
__device__ __forceinline__ int cvtpk(float lo, float hi){
  int d; asm("v_cvt_pk_bf16_f32 %0, %1, %2" : "=v"(d) : "v"(lo), "v"(hi)); return d;
}
__device__ __forceinline__ void gload16(const void* g, void* l){
  __builtin_amdgcn_global_load_lds((const __attribute__((address_space(1))) unsigned int*)g,
                                   (__attribute__((address_space(3))) unsigned int*)l, 16, 0, 0);
}

// ---------------- modulation MLP (fp32, tiny) ----------------
__global__ __launch_bounds__(256) void mod_stage1_k(
    const float* __restrict__ p_emb, const float* __restrict__ w1,
    const float* __restrict__ b1, float* __restrict__ h2){
  __shared__ float sp[1024];
  const int b = blockIdx.x >> 1;
  const int obase = (blockIdx.x & 1) * 256;
  for (int i = threadIdx.x; i < 1024; i += 256)
    sp[i] = siluf(p_emb[b*1024 + i]);
  __syncthreads();
  const int o = obase + threadIdx.x;
  float acc = 0.f;
  for (int j = 0; j < 1024; ++j) acc += sp[j] * w1[j*512 + o];
  h2[b*512 + o] = siluf(acc + b1[o]);
}

__global__ __launch_bounds__(256) void mod_stage2_k(
    const float* __restrict__ h2, const float* __restrict__ w2,
    const float* __restrict__ b2, float* __restrict__ mod){
  __shared__ float sh[512];
  const int b = blockIdx.x / 36;
  const int obase = (blockIdx.x % 36) * 256;
  for (int i = threadIdx.x; i < 512; i += 256)
    sh[i] = h2[b*512 + i];
  __syncthreads();
  const int o = obase + threadIdx.x;
  float acc = 0.f;
  for (int j = 0; j < 512; ++j) acc += sh[j] * w2[j*9216 + o];
  mod[b*9216 + o] = acc + b2[o];
}

// ------------- fused weight convert+transpose (all 7 weights, 1 launch) -----
__global__ __launch_bounds__(256) void wt_all_k(
    const float* __restrict__ s0, u16* __restrict__ d0,
    const float* __restrict__ s1, u16* __restrict__ d1,
    const float* __restrict__ s2, u16* __restrict__ d2,
    const float* __restrict__ s3, u16* __restrict__ d3,
    const float* __restrict__ s4, u16* __restrict__ d4,
    const float* __restrict__ s5, u16* __restrict__ d5,
    const float* __restrict__ s6, u16* __restrict__ d6){
  const int bid = blockIdx.x;
  const float* S; u16* D; int K, N, lid;
  if      (bid < 1728) { S=s0; D=d0; K=768;  N=2304; lid=bid; }
  else if (bid < 3456) { S=s1; D=d1; K=768;  N=2304; lid=bid-1728; }
  else if (bid < 4032) { S=s2; D=d2; K=768;  N=768;  lid=bid-3456; }
  else if (bid < 6336) { S=s3; D=d3; K=768;  N=3072; lid=bid-4032; }
  else if (bid < 8640) { S=s4; D=d4; K=3072; N=768;  lid=bid-6336; }
  else if (bid < 10944){ S=s5; D=d5; K=768;  N=3072; lid=bid-8640; }
  else                 { S=s6; D=d6; K=3072; N=768;  lid=bid-10944; }
  const int nx = N >> 5;
  const int k0 = (lid / nx) * 32, n0 = (lid % nx) * 32;
  __shared__ float t[32][33];
  const int tx = threadIdx.x & 31, ty = threadIdx.x >> 5;
  for (int i = ty; i < 32; i += 8)
    t[i][tx] = S[(size_t)(k0+i)*N + n0 + tx];
  __syncthreads();
  for (int i = ty; i < 32; i += 8)
    D[(size_t)(n0+i)*K + k0 + tx] = f2b(t[tx][i]);
}

// ---------------- RMSNorm + modulation -> bf16 (both streams, 1 launch) ----
__global__ __launch_bounds__(256) void rmsnorm2_k(
    const float* __restrict__ x0, const float* __restrict__ w0, int cs0, int ch0, u16* __restrict__ o0,
    const float* __restrict__ x1, const float* __restrict__ w1, int cs1, int ch1, u16* __restrict__ o1,
    const float* __restrict__ mod){
  const int rowg = blockIdx.x;
  const int s = rowg >> 11;
  const int row = rowg & 2047;
  const float* x = s ? x1 : x0;
  const float* w = s ? w1 : w0;
  const int cs = s ? cs1 : cs0, ch = s ? ch1 : ch0;
  u16* out = s ? o1 : o0;
  const int b = row >> 10;
  const int tid = threadIdx.x;
  const float* xr = x + (size_t)row * DIMM;
  float v0 = xr[tid], v1 = xr[tid + 256], v2 = xr[tid + 512];
  float ss = v0*v0 + v1*v1 + v2*v2;
  __shared__ float red[4];
  for (int m = 1; m < 64; m <<= 1) ss += __shfl_xor(ss, m, 64);
  if ((tid & 63) == 0) red[tid >> 6] = ss;
  __syncthreads();
  float tot = red[0] + red[1] + red[2] + red[3];
  float rms = rsqrtf(tot * (1.f/768.f) + kEps);
  const float* ms = mod + (size_t)b*9216 + (size_t)cs*768;
  const float* mh = mod + (size_t)b*9216 + (size_t)ch*768;
  u16* orow = out + (size_t)row * DIMM;
  orow[tid]       = f2b(v0*rms*w[tid]      *(1.f+ms[tid])       + mh[tid]);
  orow[tid + 256] = f2b(v1*rms*w[tid+256]  *(1.f+ms[tid+256])   + mh[tid+256]);
  orow[tid + 512] = f2b(v2*rms*w[tid+512]  *(1.f+ms[tid+512])   + mh[tid+512]);
}

// ---------------- 4-wave bf16 MFMA GEMM (big grids: QKV, MLP-up) -----------
// A[M,K] bf16 row-major, Bt[N,K] bf16 row-major. 128x128 tile, BK=32.
// EPI: 1 = bf16 store; 2 = gelu->bf16 store.
template<int EPI, int DUAL>
__global__ __launch_bounds__(256) void gemm_bf16_k(
    const u16* __restrict__ A0, const u16* __restrict__ Bt0,
    const float* __restrict__ bias0, void* __restrict__ C0,
    const u16* __restrict__ A1, const u16* __restrict__ Bt1,
    const float* __restrict__ bias1, void* __restrict__ C1,
    int M, int N, int K){
  __shared__ u16 As[2][128*32];
  __shared__ u16 Bs[2][128*32];
  const int z = DUAL ? blockIdx.z : 0;
  const u16* A      = z ? A1 : A0;
  const u16* Bt     = z ? Bt1 : Bt0;
  const float* bias = z ? bias1 : bias0;
  void* C           = z ? C1 : C0;
  const int tid = threadIdx.x;
  const int w = tid >> 6, l = tid & 63;
  const int m0 = blockIdx.y*128, n0 = blockIdx.x*128;
  const int wr = w >> 1, wc = w & 1;
  const int la = l & 15, hi4 = l >> 4;
  f32x4 acc[4][4] = {};
  const int nk = K >> 5;
  #pragma unroll
  for (int it = 0; it < 2; ++it){
    const int sb = w*128 + it*64;
    const int s = sb + l;
    const int row = s >> 2, sl = s & 3;
    gload16(A  + (size_t)(m0+row)*K + sl*8, &As[0][sb*8]);
    gload16(Bt + (size_t)(n0+row)*K + sl*8, &Bs[0][sb*8]);
  }
  __syncthreads();
  for (int kt = 0; kt < nk; ++kt){
    const int cur = kt & 1;
    if (kt + 1 < nk){
      const int k0n = (kt+1) << 5;
      #pragma unroll
      for (int it = 0; it < 2; ++it){
        const int sb = w*128 + it*64;
        const int s = sb + l;
        const int row = s >> 2, sl = s & 3;
        gload16(A  + (size_t)(m0+row)*K + k0n + sl*8, &As[cur^1][sb*8]);
        gload16(Bt + (size_t)(n0+row)*K + k0n + sl*8, &Bs[cur^1][sb*8]);
      }
    }
    short8 af[4], bf[4];
    #pragma unroll
    for (int mi = 0; mi < 4; ++mi)
      af[mi] = *(const short8*)((const char*)&As[cur][0] + (wr*64 + mi*16 + la)*64 + hi4*16);
    #pragma unroll
    for (int ni = 0; ni < 4; ++ni)
      bf[ni] = *(const short8*)((const char*)&Bs[cur][0] + (wc*64 + ni*16 + la)*64 + hi4*16);
    #pragma unroll
    for (int mi = 0; mi < 4; ++mi)
      #pragma unroll
      for (int ni = 0; ni < 4; ++ni)
        acc[mi][ni] = __builtin_amdgcn_mfma_f32_16x16x32_bf16(af[mi], bf[ni], acc[mi][ni], 0, 0, 0);
    __syncthreads();
  }
  #pragma unroll
  for (int mi = 0; mi < 4; ++mi){
    #pragma unroll
    for (int ni = 0; ni < 4; ++ni){
      const int n = n0 + wc*64 + ni*16 + la;
      const float bv = bias[n];
      #pragma unroll
      for (int rr = 0; rr < 4; ++rr){
        const int m = m0 + wr*64 + mi*16 + hi4*4 + rr;
        float v = acc[mi][ni][rr] + bv;
        if constexpr (EPI == 2) v = geluf(v);
        ((u16*)C)[(size_t)m*N + n] = f2b(v);
      }
    }
  }
}

// ---------------- 16-wave split-K=4 GEMM (192-block shapes, N=768) ---------
// 1024 threads = 4 K-groups x 4 waves; 128x128 tile; combine via LDS.
// EPI: 3 = O = X + (v)*gate (outproj+residual); 4 = O += v*gate (final add).
// Grid is 1-D 192; decoded so the 6 x-blocks sharing an A-panel share an XCD.
template<int EPI, int DUAL>
__global__ __launch_bounds__(1024) void gemm16_k(
    const u16* __restrict__ A0, const u16* __restrict__ Bt0,
    const float* __restrict__ bias0,
    const u16* __restrict__ A1, const u16* __restrict__ Bt1,
    const float* __restrict__ bias1,
    const float* __restrict__ mod, const float* __restrict__ X0,
    const float* __restrict__ X1, float* __restrict__ O0,
    float* __restrict__ O1, int cg0, int cg1,
    int M, int N, int K){
  __shared__ char lds[131072];   // 4 groups x 32KB staging; reused for combine
  const int bid = blockIdx.x;
  const int xcd = bid & 7, kk = bid >> 3;
  const int g = xcd + 8*(kk/6);      // 32 (y,z) panel groups, 6 x-blocks each
  const int x = kk % 6;
  int by, z;
  if constexpr (DUAL){ by = g & 15; z = g >> 4; } else { by = g; z = 0; }
  const u16* A      = z ? A1 : A0;
  const u16* Bt     = z ? Bt1 : Bt0;
  const float* bias = z ? bias1 : bias0;
  const int tid = threadIdx.x;
  const int w = tid >> 6, l = tid & 63;
  const int kg = w >> 2, gw = w & 3;
  const int m0 = by*128, n0 = x*128;
  const int wr = gw >> 1, wc = gw & 1;
  const int la = l & 15, hi4 = l >> 4;
  u16* AsG = (u16*)(lds + kg*32768);
  u16* BsG = (u16*)(lds + kg*32768 + 16384);
  const int Kg = K >> 2;
  const int nk = Kg >> 5;
  const int kbase = kg * Kg;
  f32x4 acc[4][4] = {};
  #pragma unroll
  for (int it = 0; it < 2; ++it){
    const int sb = gw*128 + it*64;
    const int s = sb + l;
    const int row = s >> 2, sl = s & 3;
    gload16(A  + (size_t)(m0+row)*K + kbase + sl*8, AsG + sb*8);
    gload16(Bt + (size_t)(n0+row)*K + kbase + sl*8, BsG + sb*8);
  }
  __syncthreads();
  for (int kt = 0; kt < nk; ++kt){
    const int cur = kt & 1;
    if (kt + 1 < nk){
      const int k0n = kbase + ((kt+1) << 5);
      #pragma unroll
      for (int it = 0; it < 2; ++it){
        const int sb = gw*128 + it*64;
        const int s = sb + l;
        const int row = s >> 2, sl = s & 3;
        gload16(A  + (size_t)(m0+row)*K + k0n + sl*8, AsG + (cur^1)*4096 + sb*8);
        gload16(Bt + (size_t)(n0+row)*K + k0n + sl*8, BsG + (cur^1)*4096 + sb*8);
      }
    }
    short8 af[4], bf[4];
    #pragma unroll
    for (int mi = 0; mi < 4; ++mi)
      af[mi] = *(const short8*)(AsG + cur*4096 + (wr*64 + mi*16 + la)*32 + hi4*8);
    #pragma unroll
    for (int ni = 0; ni < 4; ++ni)
      bf[ni] = *(const short8*)(BsG + cur*4096 + (wc*64 + ni*16 + la)*32 + hi4*8);
    #pragma unroll
    for (int mi = 0; mi < 4; ++mi)
      #pragma unroll
      for (int ni = 0; ni < 4; ++ni)
        acc[mi][ni] = __builtin_amdgcn_mfma_f32_16x16x32_bf16(af[mi], bf[ni], acc[mi][ni], 0, 0, 0);
    __syncthreads();
  }
  // combine the 4 K-group partials through LDS (tree: {1->0, 3->2} then {2->0})
  float* c0 = (float*)lds;
  float* c1 = (float*)(lds + 65536);
  #define WRACC(cb) { \
    _Pragma("unroll") for (int mi = 0; mi < 4; ++mi) \
    _Pragma("unroll") for (int ni = 0; ni < 4; ++ni) \
    _Pragma("unroll") for (int rr = 0; rr < 4; ++rr) \
      (cb)[(wr*64+mi*16+hi4*4+rr)*128 + wc*64+ni*16+la] = acc[mi][ni][rr]; }
  #define RDACC(cb) { \
    _Pragma("unroll") for (int mi = 0; mi < 4; ++mi) \
    _Pragma("unroll") for (int ni = 0; ni < 4; ++ni) \
    _Pragma("unroll") for (int rr = 0; rr < 4; ++rr) \
      acc[mi][ni][rr] += (cb)[(wr*64+mi*16+hi4*4+rr)*128 + wc*64+ni*16+la]; }
  if (kg == 1) WRACC(c0);
  if (kg == 3) WRACC(c1);
  __syncthreads();
  if (kg == 0) RDACC(c0);
  if (kg == 2) RDACC(c1);
  __syncthreads();
  if (kg == 2) WRACC(c0);
  __syncthreads();
  if (kg == 0){
    RDACC(c0);
    #pragma unroll
    for (int mi = 0; mi < 4; ++mi){
      #pragma unroll
      for (int ni = 0; ni < 4; ++ni){
        const int n = n0 + wc*64 + ni*16 + la;
        const float bv = bias[n];
        #pragma unroll
        for (int rr = 0; rr < 4; ++rr){
          const int m = m0 + wr*64 + mi*16 + hi4*4 + rr;
          float v = acc[mi][ni][rr] + bv;
          if constexpr (EPI == 3){
            const int bb = m >> 11, ss = (m >> 10) & 1, t = m & 1023;
            const float* X = ss ? X1 : X0;
            float* O = ss ? O1 : O0;
            const float gmod = mod[(size_t)bb*9216 + (size_t)(ss ? cg1 : cg0)*768 + n];
            const size_t oi = ((size_t)(bb*1024 + t))*768 + n;
            O[oi] = X[oi] + v*gmod;
          } else {
            float* O = z ? O1 : O0;
            const int cg = z ? cg1 : cg0;
            const int bb = m >> 10;
            const float gmod = mod[(size_t)bb*9216 + (size_t)cg*768 + n];
            O[(size_t)m*N + n] += v*gmod;
          }
        }
      }
    }
  }
  #undef WRACC
  #undef RDACC
}

// ---------------- head split + RoPE + L2norm*scale (bf16 io) ---------------
__global__ __launch_bounds__(256) void build_qkv_k(
    const u16* __restrict__ qkv1, const u16* __restrict__ qkv2,
    const float* __restrict__ qk_scale,
    u16* __restrict__ Q, u16* __restrict__ K, u16* __restrict__ V){
  const int wid = threadIdx.x >> 6;
  const int lane = threadIdx.x & 63;
  const int row = blockIdx.x * 4 + wid;         // (b*8+h)*2048 + n
  const int n = row & 2047;
  const int h = (row >> 11) & 7;
  const int b = row >> 14;
  const u16* src = (n < TT) ? (qkv1 + ((size_t)b*TT + n) * 2304)
                            : (qkv2 + ((size_t)b*TT + (n - TT)) * 2304);
  const int col = h * DHH;
  const bool act = lane < 48;
  float q0=0,q1=0,k0=0,k1=0,v0=0,v1=0,c=1.f,s=0.f,sc0=0,sc1=0;
  if (act){
    q0 = b2f(src[col + lane]);        q1 = b2f(src[col + lane + 48]);
    k0 = b2f(src[768 + col + lane]);  k1 = b2f(src[768 + col + lane + 48]);
    v0 = b2f(src[1536 + col + lane]); v1 = b2f(src[1536 + col + lane + 48]);
    float inv = bf16_rne((float)(1.0 / pow(10000.0, (2.0 * lane) / 96.0)));
    float ang = (float)n * inv;
    c = cosf(ang); s = sinf(ang);
    sc0 = qk_scale[lane]; sc1 = qk_scale[lane + 48];
  }
  float qr0 = q0*c - q1*s, qr1 = q1*c + q0*s;
  float kr0 = k0*c - k1*s, kr1 = k1*c + k0*s;
  float ssq = qr0*qr0 + qr1*qr1;
  float ssk = kr0*kr0 + kr1*kr1;
  for (int m = 1; m < 64; m <<= 1){ ssq += __shfl_xor(ssq, m, 64); ssk += __shfl_xor(ssk, m, 64); }
  float rq = 1.f / fmaxf(sqrtf(ssq), 1e-12f);
  float rk = 1.f / fmaxf(sqrtf(ssk), 1e-12f);
  const float sscale = 0.1020620726159658f;  // 96^-0.5 folded into Q
  if (act){
    size_t base = (size_t)row * DHH;
    Q[base + lane]      = f2b(qr0*rq*sc0*sscale);  Q[base + lane + 48] = f2b(qr1*rq*sc1*sscale);
    K[base + lane]      = f2b(kr0*rk*sc0);         K[base + lane + 48] = f2b(kr1*rk*sc1);
    V[base + lane]      = f2b(v0);                 V[base + lane + 48] = f2b(v1);
  }
}

// ---------------- V transpose: Vtmp[bh][n][96] -> Vt[bh][96][2048] ----------
__global__ __launch_bounds__(256) void vtrans_k(
    const u16* __restrict__ Vtmp, u16* __restrict__ Vt){
  __shared__ u16 t[32][33];
  const int bh = blockIdx.z;
  const int n0 = blockIdx.x*32, d0 = blockIdx.y*32;
  const int tx = threadIdx.x & 31, ty = threadIdx.x >> 5;
  for (int i = ty; i < 32; i += 8)
    t[i][tx] = Vtmp[((size_t)bh*NN + n0+i)*DHH + d0 + tx];
  __syncthreads();
  for (int i = ty; i < 32; i += 8)
    Vt[((size_t)bh*DHH + d0+i)*NN + n0 + tx] = t[tx][i];
}

// ---------------- MFMA flash attention, 8 waves = 2 KV-split groups --------
#define CROW(r) (((r)&3) + 8*((r)>>2) + 4*hi)
#define SMAXC 10.5f
#define BUILD_PA(dst, vec, basei) { \
  int a1_ = cvtpk(vec[basei+0], vec[basei+1]); \
  int b1_ = cvtpk(vec[basei+4], vec[basei+5]); \
  asm("v_permlane32_swap_b32 %0, %1" : "+v"(a1_), "+v"(b1_)); \
  int a2_ = cvtpk(vec[basei+2], vec[basei+3]); \
  int b2_ = cvtpk(vec[basei+6], vec[basei+7]); \
  asm("v_permlane32_swap_b32 %0, %1" : "+v"(a2_), "+v"(b2_)); \
  S8I4 u_; u_.i = (int4v){a1_, a2_, b1_, b2_}; dst = u_.s; }

__global__ __launch_bounds__(512) void attn_mfma_k(
    const u16* __restrict__ Qg, const u16* __restrict__ Kg,
    const u16* __restrict__ Vtg, u16* __restrict__ AO){
  __shared__ u16 Ks[2][2][64*128];   // [group][buf]; 64 rows x 256B, XOR-swizzled
  __shared__ u16 Vs[2][2][96*64];    // [group][buf]; 96 rows x 128B, XOR-swizzled
  const int bh = blockIdx.x >> 4;
  const int qblk = blockIdx.x & 15;
  const int b = bh >> 3, h = bh & 7;
  const int tid = threadIdx.x;
  const int w = tid >> 6, l = tid & 63;
  const int g2 = w >> 2, wq = w & 3;
  const int gtid = tid & 255;
  const int hi = l >> 5, li = l & 31;
  const int q0w = qblk*128 + wq*32;
  const int kvbase = g2 * 1024;

  short8 qf[6];
  {
    const u16* qrow = Qg + ((size_t)bh*NN + q0w + li)*DHH;
    #pragma unroll
    for (int ks = 0; ks < 6; ++ks)
      qf[ks] = *(const short8*)(qrow + ks*16 + hi*8);
  }

  f32x16 o0, o1, o2;
  #pragma unroll
  for (int r = 0; r < 16; ++r){ o0[r]=0.f; o1[r]=0.f; o2[r]=0.f; }
  float lrun = 0.f;

  {
    #pragma unroll
    for (int it = 0; it < 3; ++it){
      const int s = gtid + it*256;
      const int krow = s/12, ksl = s%12;
      short8 kv = *(const short8*)(Kg + ((size_t)bh*NN + kvbase + krow)*DHH + ksl*8);
      *(short8*)((char*)&Ks[g2][0][0] + krow*256 + ((ksl ^ (krow&7))<<4)) = kv;
      const int vrow = s >> 3, vsl = s & 7;
      short8 vv = *(const short8*)(Vtg + ((size_t)bh*DHH + vrow)*NN + kvbase + vsl*8);
      *(short8*)((char*)&Vs[g2][0][0] + vrow*128 + ((vsl ^ (vrow&7))<<4)) = vv;
    }
  }
  __syncthreads();

  const int NT2 = 16;
  for (int t = 0; t < NT2; ++t){
    const int cur = t & 1;
    short8 kst[3], vst[3];
    if (t + 1 < NT2){
      const int kv0 = kvbase + (t+1)*64;
      #pragma unroll
      for (int it = 0; it < 3; ++it){
        const int s = gtid + it*256;
        const int krow = s/12, ksl = s%12;
        kst[it] = *(const short8*)(Kg + ((size_t)bh*NN + kv0 + krow)*DHH + ksl*8);
        const int vrow = s >> 3, vsl = s & 7;
        vst[it] = *(const short8*)(Vtg + ((size_t)bh*DHH + vrow)*NN + kv0 + vsl*8);
      }
    }
    f32x16 s0, s1;
    #pragma unroll
    for (int r = 0; r < 16; ++r){ s0[r]=0.f; s1[r]=0.f; }
    #pragma unroll
    for (int ks = 0; ks < 6; ++ks){
      const int sl = ks*2 + hi;
      short8 kf0 = *(const short8*)((const char*)&Ks[g2][cur][0] + li*256      + ((sl ^ (li&7))<<4));
      short8 kf1 = *(const short8*)((const char*)&Ks[g2][cur][0] + (32+li)*256 + ((sl ^ ((32+li)&7))<<4));
      s0 = __builtin_amdgcn_mfma_f32_32x32x16_bf16(kf0, qf[ks], s0, 0, 0, 0);
      s1 = __builtin_amdgcn_mfma_f32_32x32x16_bf16(kf1, qf[ks], s1, 0, 0, 0);
    }
    float ps = 0.f;
    #pragma unroll
    for (int r = 0; r < 16; ++r){
      float pa = __expf(s0[r] - SMAXC);
      float pb = __expf(s1[r] - SMAXC);
      s0[r] = pa; s1[r] = pb; ps += pa + pb;
    }
    ps += __shfl_xor(ps, 32);
    lrun += ps;
    short8 pa0, pa1, pa2, pa3;
    BUILD_PA(pa0, s0, 0); BUILD_PA(pa1, s0, 8);
    BUILD_PA(pa2, s1, 0); BUILD_PA(pa3, s1, 8);
    #pragma unroll
    for (int dt = 0; dt < 3; ++dt){
      const int drow = dt*32 + li;
      const char* vb_base = (const char*)&Vs[g2][cur][0] + drow*128;
      f32x16* op = (dt==0)? &o0 : (dt==1)? &o1 : &o2;
      {
        short8 vb = *(const short8*)(vb_base + (((0*2+hi) ^ (drow&7))<<4));
        *op = __builtin_amdgcn_mfma_f32_32x32x16_bf16(pa0, vb, *op, 0, 0, 0);
      }
      {
        short8 vb = *(const short8*)(vb_base + (((1*2+hi) ^ (drow&7))<<4));
        *op = __builtin_amdgcn_mfma_f32_32x32x16_bf16(pa1, vb, *op, 0, 0, 0);
      }
      {
        short8 vb = *(const short8*)(vb_base + (((2*2+hi) ^ (drow&7))<<4));
        *op = __builtin_amdgcn_mfma_f32_32x32x16_bf16(pa2, vb, *op, 0, 0, 0);
      }
      {
        short8 vb = *(const short8*)(vb_base + (((3*2+hi) ^ (drow&7))<<4));
        *op = __builtin_amdgcn_mfma_f32_32x32x16_bf16(pa3, vb, *op, 0, 0, 0);
      }
    }
    __syncthreads();
    if (t + 1 < NT2){
      #pragma unroll
      for (int it = 0; it < 3; ++it){
        const int s = gtid + it*256;
        const int krow = s/12, ksl = s%12;
        *(short8*)((char*)&Ks[g2][cur^1][0] + krow*256 + ((ksl ^ (krow&7))<<4)) = kst[it];
        const int vrow = s >> 3, vsl = s & 7;
        *(short8*)((char*)&Vs[g2][cur^1][0] + vrow*128 + ((vsl ^ (vrow&7))<<4)) = vst[it];
      }
      __syncthreads();
    }
  }

  float* cmb = (float*)&Ks[0][0][0];
  float* cl  = (float*)&Vs[0][0][0];
  if (g2 == 1){
    #pragma unroll
    for (int r = 0; r < 16; ++r){
      cmb[((wq*16 + r)*3 + 0)*64 + l] = o0[r];
      cmb[((wq*16 + r)*3 + 1)*64 + l] = o1[r];
      cmb[((wq*16 + r)*3 + 2)*64 + l] = o2[r];
    }
    if (l < 32) cl[wq*32 + l] = lrun;
  }
  __syncthreads();
  if (g2 == 0){
    #pragma unroll
    for (int r = 0; r < 16; ++r){
      o0[r] += cmb[((wq*16 + r)*3 + 0)*64 + l];
      o1[r] += cmb[((wq*16 + r)*3 + 1)*64 + l];
      o2[r] += cmb[((wq*16 + r)*3 + 2)*64 + l];
    }
    lrun += cl[wq*32 + li];
    const float linv = 1.f / lrun;
    #pragma unroll
    for (int r = 0; r < 16; ++r){
      const float lr = __shfl(linv, CROW(r), 64);
      const int n = q0w + CROW(r);
      u16* dst = AO + ((size_t)b*NN + n)*DIMM + h*DHH + li;
      dst[0]  = f2b(o0[r]*lr);
      dst[32] = f2b(o1[r]*lr);
      dst[64] = f2b(o2[r]*lr);
    }
  }
}

// ---------------- workspace layout (bytes) ----------------
static constexpr size_t W_QKV1T = 0;
static constexpr size_t W_QKV2T = W_QKV1T + 3538944;
static constexpr size_t W_OUTT  = W_QKV2T + 3538944;
static constexpr size_t W_M1W1T = W_OUTT  + 1179648;
static constexpr size_t W_M1W2T = W_M1W1T + 4718592;
static constexpr size_t W_M2W1T = W_M1W2T + 4718592;
static constexpr size_t W_M2W2T = W_M2W1T + 4718592;
static constexpr size_t O_MODH  = W_M2W2T + 4718592;
static constexpr size_t O_MODB  = O_MODH + 4096;
static constexpr size_t DYN     = O_MODB + 73728;
static constexpr size_t O_XM1   = DYN;
static constexpr size_t O_XM2   = O_XM1 + 3145728;
static constexpr size_t O_QKV1  = O_XM2 + 3145728;
static constexpr size_t O_QKV2  = O_QKV1 + 9437184;
static constexpr size_t O_QB    = O_QKV2 + 9437184;
static constexpr size_t O_KB    = O_QB + 6291456;
static constexpr size_t O_VTMP  = O_KB + 6291456;
static constexpr size_t O_PF    = O_VTMP + 6291456;
static constexpr size_t O_VT    = O_QKV1;
static constexpr size_t O_AO    = O_QKV2;
static constexpr size_t O_H1    = O_QB;
static constexpr size_t O_H2    = O_PF;

extern "C" void kernel_launch(void* const* d_in, const int* in_sizes, int n_in,
                              void* d_out, int out_size, void* d_ws, size_t ws_size,
                              hipStream_t stream){
  const float* x_s1   = (const float*)d_in[0];
  const float* x_s2   = (const float*)d_in[1];
  const float* p_emb  = (const float*)d_in[2];
  const float* mod_w1 = (const float*)d_in[3];
  const float* mod_b1 = (const float*)d_in[4];
  const float* mod_w2 = (const float*)d_in[5];
  const float* mod_b2 = (const float*)d_in[6];
  const float* n11_w  = (const float*)d_in[7];
  const float* n12_w  = (const float*)d_in[8];
  const float* qkv_w  = (const float*)d_in[9];
  const float* qkv_b  = (const float*)d_in[10];
  const float* qkv2_w = (const float*)d_in[11];
  const float* qkv2_b = (const float*)d_in[12];
  const float* qk_sc  = (const float*)d_in[13];
  const float* out_w  = (const float*)d_in[14];
  const float* out_b  = (const float*)d_in[15];
  const float* n21_w  = (const float*)d_in[16];
  const float* n22_w  = (const float*)d_in[17];
  const float* m1w1   = (const float*)d_in[18];
  const float* m1b1   = (const float*)d_in[19];
  const float* m1w2   = (const float*)d_in[20];
  const float* m1b2   = (const float*)d_in[21];
  const float* m2w1   = (const float*)d_in[22];
  const float* m2b1   = (const float*)d_in[23];
  const float* m2w2   = (const float*)d_in[24];
  const float* m2b2   = (const float*)d_in[25];

  char* ws = (char*)d_ws;
  u16* qkv1t = (u16*)(ws + W_QKV1T);
  u16* qkv2t = (u16*)(ws + W_QKV2T);
  u16* outt  = (u16*)(ws + W_OUTT);
  u16* w11t  = (u16*)(ws + W_M1W1T);
  u16* w12t  = (u16*)(ws + W_M1W2T);
  u16* w21t  = (u16*)(ws + W_M2W1T);
  u16* w22t  = (u16*)(ws + W_M2W2T);
  float* h2b  = (float*)(ws + O_MODH);
  float* modb = (float*)(ws + O_MODB);
  u16* xm1  = (u16*)(ws + O_XM1);
  u16* xm2  = (u16*)(ws + O_XM2);
  u16* qkv1 = (u16*)(ws + O_QKV1);
  u16* qkv2 = (u16*)(ws + O_QKV2);
  u16* Qb   = (u16*)(ws + O_QB);
  u16* Kb   = (u16*)(ws + O_KB);
  u16* Vtmp = (u16*)(ws + O_VTMP);
  u16* Vt   = (u16*)(ws + O_VT);
  u16* AO   = (u16*)(ws + O_AO);
  u16* H1   = (u16*)(ws + O_H1);
  u16* H2   = (u16*)(ws + O_H2);

  float* out0 = (float*)d_out;
  float* out1 = out0 + (size_t)BB*TT*DIMM;

  wt_all_k<<<13248, 256, 0, stream>>>(qkv_w, qkv1t, qkv2_w, qkv2t, out_w, outt,
                                      m1w1, w11t, m1w2, w12t, m2w1, w21t, m2w2, w22t);

  mod_stage1_k<<<4, 256, 0, stream>>>(p_emb, mod_w1, mod_b1, h2b);
  mod_stage2_k<<<72, 256, 0, stream>>>(h2b, mod_w2, mod_b2, modb);

  rmsnorm2_k<<<2*BB*TT, 256, 0, stream>>>(x_s1, n11_w, 0, 1, xm1,
                                          x_s2, n12_w, 3, 4, xm2, modb);

  gemm_bf16_k<1,1><<<dim3(18, 16, 2), 256, 0, stream>>>(
      xm1, qkv1t, qkv_b, qkv1, xm2, qkv2t, qkv2_b, qkv2, 2048, 2304, 768);

  build_qkv_k<<<(BB*NHEADS*NN)/4, 256, 0, stream>>>(qkv1, qkv2, qk_sc, Qb, Kb, Vtmp);

  vtrans_k<<<dim3(NN/32, DHH/32, 16), 256, 0, stream>>>(Vtmp, Vt);

  attn_mfma_k<<<16*16, 512, 0, stream>>>(Qb, Kb, Vt, AO);

  // out projection + fused gated residual -> d_out (16-wave split-K)
  gemm16_k<3,0><<<192, 1024, 0, stream>>>(
      AO, outt, out_b, AO, outt, out_b,
      modb, x_s1, x_s2, out0, out1, 2, 5, 4096, 768, 768);

  rmsnorm2_k<<<2*BB*TT, 256, 0, stream>>>(out0, n21_w, 6, 7, xm1,
                                          out1, n22_w, 9, 10, xm2, modb);

  gemm_bf16_k<2,1><<<dim3(24, 16, 2), 256, 0, stream>>>(
      xm1, w11t, m1b1, H1, xm2, w21t, m2b1, H2, 2048, 3072, 768);

  // MLP down (dual) + fused final gated add (16-wave split-K)
  gemm16_k<4,1><<<192, 1024, 0, stream>>>(
      H1, w12t, m1b2, H2, w22t, m2b2,
      modb, nullptr, nullptr, out0, out1, 8, 11, 2048, 768, 3072);
}